// Round 13
// baseline (182.751 us; speedup 1.0000x reference)
//
#include <hip/hip_runtime.h>
#include <hip/hip_bf16.h>

#define N_Q   10000
#define N_CAM 6
#define HIMG  60
#define WIMG  100
#define NPIX  6000

typedef __attribute__((ext_vector_type(4))) float f32x4;
typedef __attribute__((ext_vector_type(2))) float f32x2;
typedef __attribute__((ext_vector_type(8))) short bf16x8;

__device__ __forceinline__ unsigned short f2bf(float x) {
  __hip_bfloat16 b = __float2bfloat16(x);
  return *reinterpret_cast<unsigned short*>(&b);
}
__device__ __forceinline__ float bf2f(unsigned short u) {
  return __uint_as_float(((unsigned)u) << 16);
}
__device__ __forceinline__ float bf16lo(unsigned int u) {
  return __uint_as_float(u << 16);
}
__device__ __forceinline__ float bf16hi(unsigned int u) {
  return __uint_as_float(u & 0xffff0000u);
}
// packed dual-FMA: acc = a * b + acc (2 channels per instruction)
__device__ __forceinline__ void pk_fma(f32x2& acc, f32x2 a, f32x2 b) {
  asm("v_pk_fma_f32 %0, %1, %2, %0" : "+v"(acc) : "v"(a), "v"(b));
}
// load 8 consecutive f32, split to bf16 hi/lo fragments in-register
__device__ __forceinline__ void split8(const float* pa, bf16x8& ah, bf16x8& al) {
  const float4 v0 = *reinterpret_cast<const float4*>(pa);
  const float4 v1 = *reinterpret_cast<const float4*>(pa + 4);
  const float v[8] = {v0.x, v0.y, v0.z, v0.w, v1.x, v1.y, v1.z, v1.w};
#pragma unroll
  for (int j = 0; j < 8; ++j) {
    const unsigned short hb = f2bf(v[j]);
    ah[j] = (short)hb;
    al[j] = (short)f2bf(v[j] - bf2f(hb));
  }
}
// split an 8-float array (non-contiguous source) to bf16 hi/lo
__device__ __forceinline__ void split8v(const float v[8], bf16x8& ah, bf16x8& al) {
#pragma unroll
  for (int j = 0; j < 8; ++j) {
    const unsigned short hb = f2bf(v[j]);
    ah[j] = (short)hb;
    al[j] = (short)f2bf(v[j] - bf2f(hb));
  }
}

// ---------------------------------------------------------------------------
// Kernel 1 (fused): feats transpose (564 blocks) + offset/logit GEMMs
// (157 m-tile blocks). Each gemm block computes ALL 6 column tiles: A (f32
// query) loaded+split once per k-step, held in registers; B (oW/wW f32,
// L2-resident) loaded scalar + split in-register. No weight-prep kernel.
// ---------------------------------------------------------------------------
#define TRANS_BLKS (N_CAM * 94)
#define G12_BLKS   ((N_Q + 63) / 64)

__global__ __launch_bounds__(256) void fused_prep_gemm_k(
    const float* __restrict__ in,   // image feats
    const float* __restrict__ q,    // f32 query
    unsigned short* __restrict__ ftout,
    const float* __restrict__ oW, const float* __restrict__ b1,
    float* __restrict__ C1,         // offs (N,256)
    const float* __restrict__ wW, const float* __restrict__ b2,
    float* __restrict__ C2) {       // wlog (N,128) = exp(logit)
  __shared__ float tile[64][65];
  const int tid = threadIdx.x;
  if (blockIdx.x < TRANS_BLKS) {
    const int cam = blockIdx.x / 94;
    const int px0 = (blockIdx.x % 94) * 64;
    const int lpx = tid & 63;
    const int cg  = tid >> 6;
    const int px  = px0 + lpx;
    const bool pv = px < NPIX;

    for (int c0 = 0; c0 < 256; c0 += 64) {
#pragma unroll
      for (int i = 0; i < 16; ++i) {
        int cc = cg * 16 + i;
        tile[lpx][cc] = pv ? in[(cam * 256 + c0 + cc) * NPIX + px] : 0.f;
      }
      __syncthreads();
      const int wc = tid & 63;
      const int pg = tid >> 6;
#pragma unroll
      for (int i = 0; i < 16; ++i) {
        int lp = pg * 16 + i;
        int gpx = px0 + lp;
        if (gpx < NPIX)
          ftout[(size_t)(cam * NPIX + gpx) * 256 + c0 + wc] = f2bf(tile[lp][wc]);
      }
      __syncthreads();
    }
    return;
  }

  // ---- GEMM part: block = one 64-row m-tile; wave w -> cols [w*96, w*96+96)
  // of the concatenated output space [0,256)=offs, [256,384)=wlog.
  const int bm = (blockIdx.x - TRANS_BLKS) * 64;
  const int l  = tid & 63;
  const int w  = tid >> 6;
  const int lr = l & 15;
  const int lk = (l >> 4) * 8;

  const float* pa[4];
#pragma unroll
  for (int rf = 0; rf < 4; ++rf) {
    const int am = min(bm + rf * 16 + lr, N_Q - 1);
    pa[rf] = q + (size_t)am * 256 + lk;
  }

  f32x4 acc[4][6] = {};

#pragma unroll
  for (int ks = 0; ks < 8; ++ks) {
    bf16x8 ah[4], al[4];
#pragma unroll
    for (int rf = 0; rf < 4; ++rf)
      split8(pa[rf] + ks * 32, ah[rf], al[rf]);
#pragma unroll
    for (int cf = 0; cf < 6; ++cf) {
      const int colu = w * 96 + cf * 16;     // wave-uniform
      const int col  = colu + lr;
      float bv[8];
      if (colu < 256) {
#pragma unroll
        for (int j = 0; j < 8; ++j)
          bv[j] = oW[(ks * 32 + lk + j) * 256 + col];
      } else {
#pragma unroll
        for (int j = 0; j < 8; ++j)
          bv[j] = wW[(ks * 32 + lk + j) * 128 + (col - 256)];
      }
      bf16x8 bh, bl;
      split8v(bv, bh, bl);
#pragma unroll
      for (int rf = 0; rf < 4; ++rf) {
        acc[rf][cf] = __builtin_amdgcn_mfma_f32_16x16x32_bf16(ah[rf], bh, acc[rf][cf], 0, 0, 0);
        acc[rf][cf] = __builtin_amdgcn_mfma_f32_16x16x32_bf16(ah[rf], bl, acc[rf][cf], 0, 0, 0);
        acc[rf][cf] = __builtin_amdgcn_mfma_f32_16x16x32_bf16(al[rf], bh, acc[rf][cf], 0, 0, 0);
      }
    }
  }

#pragma unroll
  for (int cf = 0; cf < 6; ++cf) {
    const int colu = w * 96 + cf * 16;
    const int col  = colu + lr;
    const bool isOff = colu < 256;
    const float bs = isOff ? b1[col] : b2[col - 256];
#pragma unroll
    for (int rf = 0; rf < 4; ++rf) {
      const int row0 = bm + rf * 16 + (l >> 4) * 4;
#pragma unroll
      for (int r = 0; r < 4; ++r) {
        const int row = row0 + r;
        if (row < N_Q) {
          const float v = acc[rf][cf][r] + bs;
          if (isOff) C1[(size_t)row * 256 + col] = tanhf(v) * 0.12f;
          else       C2[(size_t)row * 128 + (col - 256)] = __expf(v);
        }
      }
    }
  }
}

// ---------------------------------------------------------------------------
// Kernel 2: per-cam deformable sampling (cam-major, 2 queries x 128 thr,
// single LDS buffer). wlog = exp(logit). bf16 raw-sum partials. FROZEN (r8).
// ---------------------------------------------------------------------------
__global__ __launch_bounds__(256) void sample_cam(
    const unsigned short* __restrict__ ft, // (6,6000,256) bf16
    const float* __restrict__ offs,        // (N,256)
    const float* __restrict__ wlog,        // (N,128)  E=exp(logit)
    const float* __restrict__ refp,        // (6,N,4,2)
    const int*   __restrict__ mask,        // (6,N,4)
    unsigned short* __restrict__ partial) {// (6,N,256) bf16 raw sums
  const int tid = threadIdx.x;
  const int sub = tid >> 7;
  const int t   = tid & 127;
  const int cam = blockIdx.x / (N_Q / 2);
  const int n   = (blockIdx.x % (N_Q / 2)) * 2 + sub;
  const int h   = t >> 4;
  const int p   = t & 15;          // phase-A point
  const int pp  = p >> 2;
  const int c   = (t >> 2) & 3;    // phase-B corner
  const int ch  = t & 3;           // phase-B channel chunk

  const int vis = mask[(cam * N_Q + n) * 4 + pp];
  const unsigned long long bal = __ballot(vis != 0);
  if (!(bal & 0x1111ULL)) return;  // query invisible in this cam

  __shared__ float spt[2][1216];
  float* lds = spt[sub];
  unsigned int* ldsu = reinterpret_cast<unsigned int*>(lds);

  const float2 off = reinterpret_cast<const float2*>(offs)[n * 128 + t];
  const float E = wlog[n * 128 + t];
  const uint4* ftq2 = reinterpret_cast<const uint4*>(ft)
                      + (size_t)cam * (NPIX * 32) + (unsigned)(h * 4 + ch);

  const int abase = h * 152 + p * 9;
  const int rbase = h * 152;

  // masked softmax (pre-exponentiated): w = E*vis / sum(E*vis)
  float e = vis ? E : 0.f;
  float s = e;
#pragma unroll
  for (int m = 8; m >= 1; m >>= 1)
    s += __shfl_xor(s, m, 16);
  const float wgt = e / fmaxf(s, 1e-6f);

  // Phase A: this thread's point -> corner weights + pixel indices
  const float2 ref = reinterpret_cast<const float2*>(refp)[(cam * N_Q + n) * 4 + pp];
  const float x = fmaf(ref.x + off.x, (float)WIMG, -0.5f);
  const float y = fmaf(ref.y + off.y, (float)HIMG, -0.5f);
  const float x0f = floorf(x), y0f = floorf(y);
  const float wx = x - x0f, wy = y - y0f;
  const int x0 = (int)x0f, y0 = (int)y0f;
  const int x1 = x0 + 1, y1 = y0 + 1;
  const float mx0 = (x0 >= 0 && x0 < WIMG) ? 1.f : 0.f;
  const float mx1 = (x1 >= 0 && x1 < WIMG) ? 1.f : 0.f;
  const float my0 = (y0 >= 0 && y0 < HIMG) ? 1.f : 0.f;
  const float my1 = (y1 >= 0 && y1 < HIMG) ? 1.f : 0.f;
  const int xc0 = min(max(x0, 0), WIMG - 1);
  const int xc1 = min(max(x1, 0), WIMG - 1);
  const int yc0 = min(max(y0, 0), HIMG - 1);
  const int yc1 = min(max(y1, 0), HIMG - 1);
  lds[abase + 0] = (1.f - wx) * (1.f - wy) * mx0 * my0 * wgt;
  lds[abase + 1] = wx * (1.f - wy) * mx1 * my0 * wgt;
  lds[abase + 2] = (1.f - wx) * wy * mx0 * my1 * wgt;
  lds[abase + 3] = wx * wy * mx1 * my1 * wgt;
  ldsu[abase + 4] = (unsigned)(yc0 * WIMG + xc0);
  ldsu[abase + 5] = (unsigned)(yc0 * WIMG + xc1);
  ldsu[abase + 6] = (unsigned)(yc1 * WIMG + xc0);
  ldsu[abase + 7] = (unsigned)(yc1 * WIMG + xc1);
  __builtin_amdgcn_wave_barrier();

  // Phase B: issue ALL visible pillars' uint4 gathers, then consume (packed).
  f32x2 acc2[4] = {{0.f, 0.f}, {0.f, 0.f}, {0.f, 0.f}, {0.f, 0.f}};
  const bool pv0 = (bal      ) & 1ULL;
  const bool pv1 = (bal >>  4) & 1ULL;
  const bool pv2 = (bal >>  8) & 1ULL;
  const bool pv3 = (bal >> 12) & 1ULL;
  uint4 u0[4], u1[4], u2[4], u3[4];

#define ISSUE(U, P)                                                          \
  if (pv##P) {                                                               \
    _Pragma("unroll")                                                        \
    for (int pn = 0; pn < 4; ++pn) {                                         \
      const unsigned pix = ldsu[rbase + ((P) * 4 + pn) * 9 + 4 + c];         \
      U[pn] = ftq2[pix * 32u];                                               \
    }                                                                        \
  }
  ISSUE(u0, 0) ISSUE(u1, 1) ISSUE(u2, 2) ISSUE(u3, 3)

#define CONSUME(U, P)                                                        \
  if (pv##P) {                                                               \
    _Pragma("unroll")                                                        \
    for (int pn = 0; pn < 4; ++pn) {                                         \
      const float wv = lds[rbase + ((P) * 4 + pn) * 9 + c];                  \
      const f32x2 w2 = {wv, wv};                                             \
      f32x2 a;                                                               \
      a.x = bf16lo(U[pn].x); a.y = __uint_as_float(U[pn].x);                 \
      pk_fma(acc2[0], a, w2);                                                \
      a.x = bf16lo(U[pn].y); a.y = __uint_as_float(U[pn].y);                 \
      pk_fma(acc2[1], a, w2);                                                \
      a.x = bf16lo(U[pn].z); a.y = __uint_as_float(U[pn].z);                 \
      pk_fma(acc2[2], a, w2);                                                \
      a.x = bf16lo(U[pn].w); a.y = __uint_as_float(U[pn].w);                 \
      pk_fma(acc2[3], a, w2);                                                \
    }                                                                        \
  }
  CONSUME(u0, 0) CONSUME(u1, 1) CONSUME(u2, 2) CONSUME(u3, 3)
#undef ISSUE
#undef CONSUME

  float acc[8];
#pragma unroll
  for (int j = 0; j < 4; ++j) { acc[2 * j] = acc2[j].x; acc[2 * j + 1] = acc2[j].y; }
  // reduce over the 4 corner lanes (bits 2-3 of lane id)
#pragma unroll
  for (int j = 0; j < 8; ++j) acc[j] += __shfl_xor(acc[j], 4);
#pragma unroll
  for (int j = 0; j < 8; ++j) acc[j] += __shfl_xor(acc[j], 8);

  if (c == 0) {
    unsigned w01 = (unsigned)f2bf(acc[0]) | ((unsigned)f2bf(acc[1]) << 16);
    unsigned w23 = (unsigned)f2bf(acc[2]) | ((unsigned)f2bf(acc[3]) << 16);
    unsigned w45 = (unsigned)f2bf(acc[4]) | ((unsigned)f2bf(acc[5]) << 16);
    unsigned w67 = (unsigned)f2bf(acc[6]) | ((unsigned)f2bf(acc[7]) << 16);
    uint4 v = {w01, w23, w45, w67};
    reinterpret_cast<uint4*>(partial)[((size_t)cam * N_Q + n) * 32 + h * 4 + ch] = v;
  }
}

// ---------------------------------------------------------------------------
// Kernel 3: out-projection GEMM with FUSED cam-combine, one block per 64-row
// m-tile. Combine runs ONCE per block into LDS (partial read exactly once),
// then a 48-MFMA/k-step GEMM from LDS; B built from f32 outW in-register.
// ---------------------------------------------------------------------------
__global__ __launch_bounds__(256) void gemm_out_k(
    const unsigned short* __restrict__ partial, // (6,N,256) bf16 raw sums
    const int*   __restrict__ mask,             // (6,N,4)
    const float* __restrict__ outW,             // (256,256) f32 [k][n]
    const float* __restrict__ bias, float* __restrict__ C) {
  __shared__ unsigned short Ahs[64][264];
  __shared__ unsigned short Als[64][264];
  __shared__ float    sinv[64];
  __shared__ unsigned sbits[64];

  const int tid = threadIdx.x;
  const int bm  = blockIdx.x * 64;

  // per-row visibility summary
  if (tid < 64) {
    const int n = min(bm + tid, N_Q - 1);
    unsigned bits = 0; int cnt = 0;
#pragma unroll
    for (int cam = 0; cam < N_CAM; ++cam) {
      const int4 m4 = *reinterpret_cast<const int4*>(&mask[(cam * N_Q + n) * 4]);
      const int any = (m4.x | m4.y | m4.z | m4.w) ? 1 : 0;
      bits |= (unsigned)any << cam;
      cnt += any;
    }
    sbits[tid] = bits;
    sinv[tid]  = (cnt > 0) ? (1.f / (float)cnt) : 1.f;
  }
  __syncthreads();

  // combine: 2048 units (row, slot-of-8-channels); 8 units per thread.
  const uint4* pq = reinterpret_cast<const uint4*>(partial);
#pragma unroll
  for (int i = 0; i < 8; ++i) {
    const int u    = tid + i * 256;
    const int row  = u >> 5;
    const int slot = u & 31;
    const int n    = min(bm + row, N_Q - 1);
    const unsigned bits = sbits[row];
    const float    inv  = sinv[row];
    float v[8] = {0.f, 0.f, 0.f, 0.f, 0.f, 0.f, 0.f, 0.f};
#pragma unroll
    for (int cam = 0; cam < N_CAM; ++cam) {
      if ((bits >> cam) & 1u) {
        const uint4 x = pq[((size_t)cam * N_Q + n) * 32 + slot];
        v[0] += bf16lo(x.x); v[1] += bf16hi(x.x);
        v[2] += bf16lo(x.y); v[3] += bf16hi(x.y);
        v[4] += bf16lo(x.z); v[5] += bf16hi(x.z);
        v[6] += bf16lo(x.w); v[7] += bf16hi(x.w);
      }
    }
    unsigned short hh[8], ll[8];
#pragma unroll
    for (int j = 0; j < 8; ++j) {
      const float x = v[j] * inv;
      hh[j] = f2bf(x);
      ll[j] = f2bf(x - bf2f(hh[j]));
    }
    uint4 ph = {(unsigned)hh[0] | ((unsigned)hh[1] << 16),
                (unsigned)hh[2] | ((unsigned)hh[3] << 16),
                (unsigned)hh[4] | ((unsigned)hh[5] << 16),
                (unsigned)hh[6] | ((unsigned)hh[7] << 16)};
    uint4 pl = {(unsigned)ll[0] | ((unsigned)ll[1] << 16),
                (unsigned)ll[2] | ((unsigned)ll[3] << 16),
                (unsigned)ll[4] | ((unsigned)ll[5] << 16),
                (unsigned)ll[6] | ((unsigned)ll[7] << 16)};
    *reinterpret_cast<uint4*>(&Ahs[row][slot * 8]) = ph;
    *reinterpret_cast<uint4*>(&Als[row][slot * 8]) = pl;
  }
  __syncthreads();

  // GEMM: wave w -> cols [w*64, w*64+64); 4 row-frags x 4 col-frags.
  const int l  = tid & 63;
  const int w  = tid >> 6;
  const int lr = l & 15;
  const int lk = (l >> 4) * 8;

  f32x4 acc[4][4] = {};

#pragma unroll
  for (int ks = 0; ks < 8; ++ks) {
    bf16x8 ah[4], al[4];
#pragma unroll
    for (int rf = 0; rf < 4; ++rf) {
      ah[rf] = *reinterpret_cast<const bf16x8*>(&Ahs[rf * 16 + lr][ks * 32 + lk]);
      al[rf] = *reinterpret_cast<const bf16x8*>(&Als[rf * 16 + lr][ks * 32 + lk]);
    }
#pragma unroll
    for (int cf = 0; cf < 4; ++cf) {
      const int col = w * 64 + cf * 16 + lr;
      float bv[8];
#pragma unroll
      for (int j = 0; j < 8; ++j)
        bv[j] = outW[(ks * 32 + lk + j) * 256 + col];
      bf16x8 bh, bl;
      split8v(bv, bh, bl);
#pragma unroll
      for (int rf = 0; rf < 4; ++rf) {
        acc[rf][cf] = __builtin_amdgcn_mfma_f32_16x16x32_bf16(ah[rf], bh, acc[rf][cf], 0, 0, 0);
        acc[rf][cf] = __builtin_amdgcn_mfma_f32_16x16x32_bf16(ah[rf], bl, acc[rf][cf], 0, 0, 0);
        acc[rf][cf] = __builtin_amdgcn_mfma_f32_16x16x32_bf16(al[rf], bh, acc[rf][cf], 0, 0, 0);
      }
    }
  }

  float bias_cf[4];
#pragma unroll
  for (int cf = 0; cf < 4; ++cf) bias_cf[cf] = bias[w * 64 + cf * 16 + lr];

#pragma unroll
  for (int rf = 0; rf < 4; ++rf) {
    const int row0 = bm + rf * 16 + (l >> 4) * 4;
#pragma unroll
    for (int r = 0; r < 4; ++r) {
      const int row = row0 + r;
      if (row < N_Q) {
#pragma unroll
        for (int cf = 0; cf < 4; ++cf) {
          const int col = w * 64 + cf * 16 + lr;
          C[(size_t)row * 256 + col] = acc[rf][cf][r] + bias_cf[cf];
        }
      }
    }
  }
}

// ---------------------------------------------------------------------------
extern "C" void kernel_launch(void* const* d_in, const int* in_sizes, int n_in,
                              void* d_out, int out_size, void* d_ws, size_t ws_size,
                              hipStream_t stream) {
  const float* query = (const float*)d_in[0];
  const float* feats = (const float*)d_in[1];
  const float* refp  = (const float*)d_in[2];
  const int*   mask  = (const int*)d_in[3];
  const float* oW    = (const float*)d_in[4];
  const float* ob    = (const float*)d_in[5];
  const float* wW    = (const float*)d_in[6];
  const float* wb    = (const float*)d_in[7];
  const float* outW  = (const float*)d_in[8];
  const float* outb  = (const float*)d_in[9];
  float* out = (float*)d_out;

  char* wsb = (char*)d_ws;
  size_t o = 0;
  unsigned short* ft = (unsigned short*)(wsb + o); o += (size_t)N_CAM * NPIX * 256 * 2;
  float* offs    = (float*)(wsb + o); o += (size_t)N_Q * 256 * 4;
  float* wlog    = (float*)(wsb + o); o += (size_t)N_Q * 128 * 4;
  unsigned short* partial = (unsigned short*)(wsb + o);
  o += (size_t)N_CAM * N_Q * 256 * 2;                                      // 30.7 MB

  fused_prep_gemm_k<<<TRANS_BLKS + G12_BLKS, 256, 0, stream>>>(
      feats, query, ft, oW, ob, offs, wW, wb, wlog);

  sample_cam<<<N_CAM * (N_Q / 2), 256, 0, stream>>>(ft, offs, wlog, refp, mask,
                                                    partial);

  gemm_out_k<<<(N_Q + 63) / 64, 256, 0, stream>>>(partial, mask,
                                                  outW, outb, out);
}

// Round 14
// 144.565 us; speedup vs baseline: 1.2642x; 1.2642x over previous
//
#include <hip/hip_runtime.h>
#include <hip/hip_bf16.h>

#define N_Q   10000
#define N_CAM 6
#define HIMG  60
#define WIMG  100
#define NPIX  6000

typedef __attribute__((ext_vector_type(4))) float f32x4;
typedef __attribute__((ext_vector_type(2))) float f32x2;
typedef __attribute__((ext_vector_type(8))) short bf16x8;

__device__ __forceinline__ unsigned short f2bf(float x) {
  __hip_bfloat16 b = __float2bfloat16(x);
  return *reinterpret_cast<unsigned short*>(&b);
}
__device__ __forceinline__ float bf2f(unsigned short u) {
  return __uint_as_float(((unsigned)u) << 16);
}
__device__ __forceinline__ float bf16lo(unsigned int u) {
  return __uint_as_float(u << 16);
}
__device__ __forceinline__ float bf16hi(unsigned int u) {
  return __uint_as_float(u & 0xffff0000u);
}
// packed dual-FMA: acc = a * b + acc (2 channels per instruction)
__device__ __forceinline__ void pk_fma(f32x2& acc, f32x2 a, f32x2 b) {
  asm("v_pk_fma_f32 %0, %1, %2, %0" : "+v"(acc) : "v"(a), "v"(b));
}
// load 8 consecutive f32, split to bf16 hi/lo fragments in-register
__device__ __forceinline__ void split8(const float* pa, bf16x8& ah, bf16x8& al) {
  const float4 v0 = *reinterpret_cast<const float4*>(pa);
  const float4 v1 = *reinterpret_cast<const float4*>(pa + 4);
  const float v[8] = {v0.x, v0.y, v0.z, v0.w, v1.x, v1.y, v1.z, v1.w};
#pragma unroll
  for (int j = 0; j < 8; ++j) {
    const unsigned short hb = f2bf(v[j]);
    ah[j] = (short)hb;
    al[j] = (short)f2bf(v[j] - bf2f(hb));
  }
}

// ---------------------------------------------------------------------------
// Kernel 1 (tiny): weight transpose + hi/lo decompose. 640 blocks.
// ---------------------------------------------------------------------------
__global__ __launch_bounds__(256) void wprep_k(
    const float* __restrict__ oW, const float* __restrict__ wW,
    const float* __restrict__ outW,
    unsigned short* __restrict__ oWth,  unsigned short* __restrict__ oWtl,
    unsigned short* __restrict__ wWth,  unsigned short* __restrict__ wWtl,
    unsigned short* __restrict__ outWth,unsigned short* __restrict__ outWtl) {
  const int b = blockIdx.x, k = threadIdx.x;
  float v; unsigned short *dh, *dl; int idx;
  if (b < 256) {
    v = oW[k * 256 + b]; dh = oWth; dl = oWtl; idx = b * 256 + k;
  } else if (b < 384) {
    int nn = b - 256; v = wW[k * 128 + nn]; dh = wWth; dl = wWtl; idx = nn * 256 + k;
  } else {
    int nn = b - 384; v = outW[k * 256 + nn]; dh = outWth; dl = outWtl; idx = nn * 256 + k;
  }
  unsigned short hv = f2bf(v);
  dh[idx] = hv;
  dl[idx] = f2bf(v - bf2f(hv));
}

// ---------------------------------------------------------------------------
// MFMA GEMM body, A = f32 row-major split in-register; B pre-split bf16 hi/lo.
// mode 1: tanh(v)*0.12  2: exp(v)
// ---------------------------------------------------------------------------
__device__ __forceinline__ void gemm_bodyA32(
    const float* __restrict__ A,
    const unsigned short* __restrict__ Bh, const unsigned short* __restrict__ Bl,
    const float* __restrict__ bias, float* __restrict__ C,
    int M, int N, int mode, int bm, int bn, int tid) {
  const int l = tid & 63, w = tid >> 6;
  const int wm = w >> 1, wn = w & 1;
  const int lr = l & 15;
  const int lk = (l >> 4) * 8;

  const int am0 = min(bm + wm * 32 + lr, M - 1);
  const int am1 = min(bm + wm * 32 + 16 + lr, M - 1);
  const int bn0 = bn + wn * 32 + lr;
  const int bn1 = bn0 + 16;

  const float* pa0 = A + (size_t)am0 * 256 + lk;
  const float* pa1 = A + (size_t)am1 * 256 + lk;
  const bf16x8* pbh0 = (const bf16x8*)(Bh + (size_t)bn0 * 256 + lk);
  const bf16x8* pbh1 = (const bf16x8*)(Bh + (size_t)bn1 * 256 + lk);
  const bf16x8* pbl0 = (const bf16x8*)(Bl + (size_t)bn0 * 256 + lk);
  const bf16x8* pbl1 = (const bf16x8*)(Bl + (size_t)bn1 * 256 + lk);

  f32x4 acc00 = {}, acc01 = {}, acc10 = {}, acc11 = {};

#pragma unroll
  for (int ks = 0; ks < 8; ++ks) {
    bf16x8 ah0, al0, ah1, al1;
    split8(pa0 + ks * 32, ah0, al0);
    split8(pa1 + ks * 32, ah1, al1);
    bf16x8 bh0 = pbh0[ks * 4], bh1 = pbh1[ks * 4];
    bf16x8 bl0 = pbl0[ks * 4], bl1 = pbl1[ks * 4];
    acc00 = __builtin_amdgcn_mfma_f32_16x16x32_bf16(ah0, bh0, acc00, 0, 0, 0);
    acc00 = __builtin_amdgcn_mfma_f32_16x16x32_bf16(ah0, bl0, acc00, 0, 0, 0);
    acc00 = __builtin_amdgcn_mfma_f32_16x16x32_bf16(al0, bh0, acc00, 0, 0, 0);
    acc01 = __builtin_amdgcn_mfma_f32_16x16x32_bf16(ah0, bh1, acc01, 0, 0, 0);
    acc01 = __builtin_amdgcn_mfma_f32_16x16x32_bf16(ah0, bl1, acc01, 0, 0, 0);
    acc01 = __builtin_amdgcn_mfma_f32_16x16x32_bf16(al0, bh1, acc01, 0, 0, 0);
    acc10 = __builtin_amdgcn_mfma_f32_16x16x32_bf16(ah1, bh0, acc10, 0, 0, 0);
    acc10 = __builtin_amdgcn_mfma_f32_16x16x32_bf16(ah1, bl0, acc10, 0, 0, 0);
    acc10 = __builtin_amdgcn_mfma_f32_16x16x32_bf16(al1, bh0, acc10, 0, 0, 0);
    acc11 = __builtin_amdgcn_mfma_f32_16x16x32_bf16(ah1, bh1, acc11, 0, 0, 0);
    acc11 = __builtin_amdgcn_mfma_f32_16x16x32_bf16(ah1, bl1, acc11, 0, 0, 0);
    acc11 = __builtin_amdgcn_mfma_f32_16x16x32_bf16(al1, bh1, acc11, 0, 0, 0);
  }

  const float bias0 = bias[bn + wn * 32 + lr];
  const float bias1 = bias[bn + wn * 32 + 16 + lr];
  const int row0 = bm + wm * 32 + (l >> 4) * 4;
  const int col0 = bn + wn * 32 + lr;
#pragma unroll
  for (int r = 0; r < 4; ++r) {
    int rowA = row0 + r, rowB = row0 + 16 + r;
    float v00 = acc00[r] + bias0, v01 = acc01[r] + bias1;
    float v10 = acc10[r] + bias0, v11 = acc11[r] + bias1;
    if (mode == 1) {
      v00 = tanhf(v00) * 0.12f; v01 = tanhf(v01) * 0.12f;
      v10 = tanhf(v10) * 0.12f; v11 = tanhf(v11) * 0.12f;
    } else if (mode == 2) {
      v00 = __expf(v00); v01 = __expf(v01);
      v10 = __expf(v10); v11 = __expf(v11);
    }
    if (rowA < M) {
      C[(size_t)rowA * N + col0] = v00;
      C[(size_t)rowA * N + col0 + 16] = v01;
    }
    if (rowB < M) {
      C[(size_t)rowB * N + col0] = v10;
      C[(size_t)rowB * N + col0 + 16] = v11;
    }
  }
}

// ---------------------------------------------------------------------------
// Kernel 2 (fused): feats transpose (564 blocks) + offset/logit GEMMs
// (942 col-tile-major blocks, reading f32 query directly). r12 structure.
// ---------------------------------------------------------------------------
#define TRANS_BLKS (N_CAM * 94)
#define G12_BLKS   (157 * 6)

__global__ __launch_bounds__(256) void fused_prep_gemm_k(
    const float* __restrict__ in,   // image feats
    const float* __restrict__ q,    // f32 query
    unsigned short* __restrict__ ftout,
    const unsigned short* __restrict__ B1h, const unsigned short* __restrict__ B1l,
    const float* __restrict__ b1, float* __restrict__ C1,
    const unsigned short* __restrict__ B2h, const unsigned short* __restrict__ B2l,
    const float* __restrict__ b2, float* __restrict__ C2) {
  __shared__ float tile[64][65];
  const int tid = threadIdx.x;
  if (blockIdx.x < TRANS_BLKS) {
    const int cam = blockIdx.x / 94;
    const int px0 = (blockIdx.x % 94) * 64;
    const int lpx = tid & 63;
    const int cg  = tid >> 6;
    const int px  = px0 + lpx;
    const bool pv = px < NPIX;

    for (int c0 = 0; c0 < 256; c0 += 64) {
#pragma unroll
      for (int i = 0; i < 16; ++i) {
        int cc = cg * 16 + i;
        tile[lpx][cc] = pv ? in[(cam * 256 + c0 + cc) * NPIX + px] : 0.f;
      }
      __syncthreads();
      const int wc = tid & 63;
      const int pg = tid >> 6;
#pragma unroll
      for (int i = 0; i < 16; ++i) {
        int lp = pg * 16 + i;
        int gpx = px0 + lp;
        if (gpx < NPIX)
          ftout[(size_t)(cam * NPIX + gpx) * 256 + c0 + wc] = f2bf(tile[lp][wc]);
      }
      __syncthreads();
    }
    return;
  }
  const int b  = blockIdx.x - TRANS_BLKS;
  const int bt = b % 6;            // column tile; consecutive blocks share A
  const int bm = (b / 6) * 64;
  if (bt < 4)
    gemm_bodyA32(q, B1h, B1l, b1, C1, N_Q, 256, 1, bm, bt * 64, tid);
  else
    gemm_bodyA32(q, B2h, B2l, b2, C2, N_Q, 128, 2, bm, (bt - 4) * 64, tid);
}

// ---------------------------------------------------------------------------
// Kernel 3: per-cam deformable sampling (cam-major, 2 queries x 128 thr,
// single LDS buffer). wlog = exp(logit). bf16 raw-sum partials. FROZEN (r8).
// ---------------------------------------------------------------------------
__global__ __launch_bounds__(256) void sample_cam(
    const unsigned short* __restrict__ ft, // (6,6000,256) bf16
    const float* __restrict__ offs,        // (N,256)
    const float* __restrict__ wlog,        // (N,128)  E=exp(logit)
    const float* __restrict__ refp,        // (6,N,4,2)
    const int*   __restrict__ mask,        // (6,N,4)
    unsigned short* __restrict__ partial) {// (6,N,256) bf16 raw sums
  const int tid = threadIdx.x;
  const int sub = tid >> 7;
  const int t   = tid & 127;
  const int cam = blockIdx.x / (N_Q / 2);
  const int n   = (blockIdx.x % (N_Q / 2)) * 2 + sub;
  const int h   = t >> 4;
  const int p   = t & 15;          // phase-A point
  const int pp  = p >> 2;
  const int c   = (t >> 2) & 3;    // phase-B corner
  const int ch  = t & 3;           // phase-B channel chunk

  const int vis = mask[(cam * N_Q + n) * 4 + pp];
  const unsigned long long bal = __ballot(vis != 0);
  if (!(bal & 0x1111ULL)) return;  // query invisible in this cam

  __shared__ float spt[2][1216];
  float* lds = spt[sub];
  unsigned int* ldsu = reinterpret_cast<unsigned int*>(lds);

  const float2 off = reinterpret_cast<const float2*>(offs)[n * 128 + t];
  const float E = wlog[n * 128 + t];
  const uint4* ftq2 = reinterpret_cast<const uint4*>(ft)
                      + (size_t)cam * (NPIX * 32) + (unsigned)(h * 4 + ch);

  const int abase = h * 152 + p * 9;
  const int rbase = h * 152;

  // masked softmax (pre-exponentiated): w = E*vis / sum(E*vis)
  float e = vis ? E : 0.f;
  float s = e;
#pragma unroll
  for (int m = 8; m >= 1; m >>= 1)
    s += __shfl_xor(s, m, 16);
  const float wgt = e / fmaxf(s, 1e-6f);

  // Phase A: this thread's point -> corner weights + pixel indices
  const float2 ref = reinterpret_cast<const float2*>(refp)[(cam * N_Q + n) * 4 + pp];
  const float x = fmaf(ref.x + off.x, (float)WIMG, -0.5f);
  const float y = fmaf(ref.y + off.y, (float)HIMG, -0.5f);
  const float x0f = floorf(x), y0f = floorf(y);
  const float wx = x - x0f, wy = y - y0f;
  const int x0 = (int)x0f, y0 = (int)y0f;
  const int x1 = x0 + 1, y1 = y0 + 1;
  const float mx0 = (x0 >= 0 && x0 < WIMG) ? 1.f : 0.f;
  const float mx1 = (x1 >= 0 && x1 < WIMG) ? 1.f : 0.f;
  const float my0 = (y0 >= 0 && y0 < HIMG) ? 1.f : 0.f;
  const float my1 = (y1 >= 0 && y1 < HIMG) ? 1.f : 0.f;
  const int xc0 = min(max(x0, 0), WIMG - 1);
  const int xc1 = min(max(x1, 0), WIMG - 1);
  const int yc0 = min(max(y0, 0), HIMG - 1);
  const int yc1 = min(max(y1, 0), HIMG - 1);
  lds[abase + 0] = (1.f - wx) * (1.f - wy) * mx0 * my0 * wgt;
  lds[abase + 1] = wx * (1.f - wy) * mx1 * my0 * wgt;
  lds[abase + 2] = (1.f - wx) * wy * mx0 * my1 * wgt;
  lds[abase + 3] = wx * wy * mx1 * my1 * wgt;
  ldsu[abase + 4] = (unsigned)(yc0 * WIMG + xc0);
  ldsu[abase + 5] = (unsigned)(yc0 * WIMG + xc1);
  ldsu[abase + 6] = (unsigned)(yc1 * WIMG + xc0);
  ldsu[abase + 7] = (unsigned)(yc1 * WIMG + xc1);
  __builtin_amdgcn_wave_barrier();

  // Phase B: issue ALL visible pillars' uint4 gathers, then consume (packed).
  f32x2 acc2[4] = {{0.f, 0.f}, {0.f, 0.f}, {0.f, 0.f}, {0.f, 0.f}};
  const bool pv0 = (bal      ) & 1ULL;
  const bool pv1 = (bal >>  4) & 1ULL;
  const bool pv2 = (bal >>  8) & 1ULL;
  const bool pv3 = (bal >> 12) & 1ULL;
  uint4 u0[4], u1[4], u2[4], u3[4];

#define ISSUE(U, P)                                                          \
  if (pv##P) {                                                               \
    _Pragma("unroll")                                                        \
    for (int pn = 0; pn < 4; ++pn) {                                         \
      const unsigned pix = ldsu[rbase + ((P) * 4 + pn) * 9 + 4 + c];         \
      U[pn] = ftq2[pix * 32u];                                               \
    }                                                                        \
  }
  ISSUE(u0, 0) ISSUE(u1, 1) ISSUE(u2, 2) ISSUE(u3, 3)

#define CONSUME(U, P)                                                        \
  if (pv##P) {                                                               \
    _Pragma("unroll")                                                        \
    for (int pn = 0; pn < 4; ++pn) {                                         \
      const float wv = lds[rbase + ((P) * 4 + pn) * 9 + c];                  \
      const f32x2 w2 = {wv, wv};                                             \
      f32x2 a;                                                               \
      a.x = bf16lo(U[pn].x); a.y = __uint_as_float(U[pn].x);                 \
      pk_fma(acc2[0], a, w2);                                                \
      a.x = bf16lo(U[pn].y); a.y = __uint_as_float(U[pn].y);                 \
      pk_fma(acc2[1], a, w2);                                                \
      a.x = bf16lo(U[pn].z); a.y = __uint_as_float(U[pn].z);                 \
      pk_fma(acc2[2], a, w2);                                                \
      a.x = bf16lo(U[pn].w); a.y = __uint_as_float(U[pn].w);                 \
      pk_fma(acc2[3], a, w2);                                                \
    }                                                                        \
  }
  CONSUME(u0, 0) CONSUME(u1, 1) CONSUME(u2, 2) CONSUME(u3, 3)
#undef ISSUE
#undef CONSUME

  float acc[8];
#pragma unroll
  for (int j = 0; j < 4; ++j) { acc[2 * j] = acc2[j].x; acc[2 * j + 1] = acc2[j].y; }
  // reduce over the 4 corner lanes (bits 2-3 of lane id)
#pragma unroll
  for (int j = 0; j < 8; ++j) acc[j] += __shfl_xor(acc[j], 4);
#pragma unroll
  for (int j = 0; j < 8; ++j) acc[j] += __shfl_xor(acc[j], 8);

  if (c == 0) {
    unsigned w01 = (unsigned)f2bf(acc[0]) | ((unsigned)f2bf(acc[1]) << 16);
    unsigned w23 = (unsigned)f2bf(acc[2]) | ((unsigned)f2bf(acc[3]) << 16);
    unsigned w45 = (unsigned)f2bf(acc[4]) | ((unsigned)f2bf(acc[5]) << 16);
    unsigned w67 = (unsigned)f2bf(acc[6]) | ((unsigned)f2bf(acc[7]) << 16);
    uint4 v = {w01, w23, w45, w67};
    reinterpret_cast<uint4*>(partial)[((size_t)cam * N_Q + n) * 32 + h * 4 + ch] = v;
  }
}

// ---------------------------------------------------------------------------
// Kernel 4: out-projection GEMM with FUSED cam-combine, one block per 32-row
// m-tile (313 blocks, 33.8 KB LDS -> 2 blocks/CU). Combine runs ONCE per
// block into LDS (partial read exactly once), then 24-MFMA-triple/k-step
// GEMM from LDS with pre-split B.
// ---------------------------------------------------------------------------
#define OUT_ROWS 32

__global__ __launch_bounds__(256) void gemm_out_k(
    const unsigned short* __restrict__ partial, // (6,N,256) bf16 raw sums
    const int*   __restrict__ mask,             // (6,N,4)
    const unsigned short* __restrict__ Bh, const unsigned short* __restrict__ Bl,
    const float* __restrict__ bias, float* __restrict__ C) {
  __shared__ unsigned short Ahs[OUT_ROWS][264];
  __shared__ unsigned short Als[OUT_ROWS][264];
  __shared__ float    sinv[OUT_ROWS];
  __shared__ unsigned sbits[OUT_ROWS];

  const int tid = threadIdx.x;
  const int bm  = blockIdx.x * OUT_ROWS;

  // per-row visibility summary
  if (tid < OUT_ROWS) {
    const int n = min(bm + tid, N_Q - 1);
    unsigned bits = 0; int cnt = 0;
#pragma unroll
    for (int cam = 0; cam < N_CAM; ++cam) {
      const int4 m4 = *reinterpret_cast<const int4*>(&mask[(cam * N_Q + n) * 4]);
      const int any = (m4.x | m4.y | m4.z | m4.w) ? 1 : 0;
      bits |= (unsigned)any << cam;
      cnt += any;
    }
    sbits[tid] = bits;
    sinv[tid]  = (cnt > 0) ? (1.f / (float)cnt) : 1.f;
  }
  __syncthreads();

  // combine: 1024 units (row, slot-of-8-channels); 4 units per thread.
  const uint4* pq = reinterpret_cast<const uint4*>(partial);
#pragma unroll
  for (int i = 0; i < 4; ++i) {
    const int u    = tid + i * 256;
    const int row  = u >> 5;
    const int slot = u & 31;
    const int n    = min(bm + row, N_Q - 1);
    const unsigned bits = sbits[row];
    const float    inv  = sinv[row];
    float v[8] = {0.f, 0.f, 0.f, 0.f, 0.f, 0.f, 0.f, 0.f};
#pragma unroll
    for (int cam = 0; cam < N_CAM; ++cam) {
      if ((bits >> cam) & 1u) {
        const uint4 x = pq[((size_t)cam * N_Q + n) * 32 + slot];
        v[0] += bf16lo(x.x); v[1] += bf16hi(x.x);
        v[2] += bf16lo(x.y); v[3] += bf16hi(x.y);
        v[4] += bf16lo(x.z); v[5] += bf16hi(x.z);
        v[6] += bf16lo(x.w); v[7] += bf16hi(x.w);
      }
    }
    unsigned short hh[8], ll[8];
#pragma unroll
    for (int j = 0; j < 8; ++j) {
      const float x = v[j] * inv;
      hh[j] = f2bf(x);
      ll[j] = f2bf(x - bf2f(hh[j]));
    }
    uint4 ph = {(unsigned)hh[0] | ((unsigned)hh[1] << 16),
                (unsigned)hh[2] | ((unsigned)hh[3] << 16),
                (unsigned)hh[4] | ((unsigned)hh[5] << 16),
                (unsigned)hh[6] | ((unsigned)hh[7] << 16)};
    uint4 pl = {(unsigned)ll[0] | ((unsigned)ll[1] << 16),
                (unsigned)ll[2] | ((unsigned)ll[3] << 16),
                (unsigned)ll[4] | ((unsigned)ll[5] << 16),
                (unsigned)ll[6] | ((unsigned)ll[7] << 16)};
    *reinterpret_cast<uint4*>(&Ahs[row][slot * 8]) = ph;
    *reinterpret_cast<uint4*>(&Als[row][slot * 8]) = pl;
  }
  __syncthreads();

  // GEMM: wave w -> cols [w*64, w*64+64); 2 row-frags x 4 col-frags.
  const int l  = tid & 63;
  const int w  = tid >> 6;
  const int lr = l & 15;
  const int lk = (l >> 4) * 8;

  const bf16x8* pbh[4];
  const bf16x8* pbl[4];
#pragma unroll
  for (int cf = 0; cf < 4; ++cf) {
    const int col = w * 64 + cf * 16 + lr;
    pbh[cf] = (const bf16x8*)(Bh + (size_t)col * 256 + lk);
    pbl[cf] = (const bf16x8*)(Bl + (size_t)col * 256 + lk);
  }

  f32x4 acc[2][4] = {};

#pragma unroll
  for (int ks = 0; ks < 8; ++ks) {
    bf16x8 ah[2], al[2], bh[4], bl[4];
#pragma unroll
    for (int rf = 0; rf < 2; ++rf) {
      ah[rf] = *reinterpret_cast<const bf16x8*>(&Ahs[rf * 16 + lr][ks * 32 + lk]);
      al[rf] = *reinterpret_cast<const bf16x8*>(&Als[rf * 16 + lr][ks * 32 + lk]);
    }
#pragma unroll
    for (int cf = 0; cf < 4; ++cf) {
      bh[cf] = pbh[cf][ks * 4];
      bl[cf] = pbl[cf][ks * 4];
    }
#pragma unroll
    for (int rf = 0; rf < 2; ++rf)
#pragma unroll
      for (int cf = 0; cf < 4; ++cf) {
        acc[rf][cf] = __builtin_amdgcn_mfma_f32_16x16x32_bf16(ah[rf], bh[cf], acc[rf][cf], 0, 0, 0);
        acc[rf][cf] = __builtin_amdgcn_mfma_f32_16x16x32_bf16(ah[rf], bl[cf], acc[rf][cf], 0, 0, 0);
        acc[rf][cf] = __builtin_amdgcn_mfma_f32_16x16x32_bf16(al[rf], bh[cf], acc[rf][cf], 0, 0, 0);
      }
  }

  float bias_cf[4];
#pragma unroll
  for (int cf = 0; cf < 4; ++cf) bias_cf[cf] = bias[w * 64 + cf * 16 + lr];

#pragma unroll
  for (int rf = 0; rf < 2; ++rf) {
    const int row0 = bm + rf * 16 + (l >> 4) * 4;
#pragma unroll
    for (int r = 0; r < 4; ++r) {
      const int row = row0 + r;
      if (row < N_Q) {
#pragma unroll
        for (int cf = 0; cf < 4; ++cf) {
          const int col = w * 64 + cf * 16 + lr;
          C[(size_t)row * 256 + col] = acc[rf][cf][r] + bias_cf[cf];
        }
      }
    }
  }
}

// ---------------------------------------------------------------------------
extern "C" void kernel_launch(void* const* d_in, const int* in_sizes, int n_in,
                              void* d_out, int out_size, void* d_ws, size_t ws_size,
                              hipStream_t stream) {
  const float* query = (const float*)d_in[0];
  const float* feats = (const float*)d_in[1];
  const float* refp  = (const float*)d_in[2];
  const int*   mask  = (const int*)d_in[3];
  const float* oW    = (const float*)d_in[4];
  const float* ob    = (const float*)d_in[5];
  const float* wW    = (const float*)d_in[6];
  const float* wb    = (const float*)d_in[7];
  const float* outW  = (const float*)d_in[8];
  const float* outb  = (const float*)d_in[9];
  float* out = (float*)d_out;

  char* wsb = (char*)d_ws;
  size_t o = 0;
  unsigned short* ft = (unsigned short*)(wsb + o); o += (size_t)N_CAM * NPIX * 256 * 2;
  unsigned short* oWth  = (unsigned short*)(wsb + o); o += 256 * 256 * 2;
  unsigned short* oWtl  = (unsigned short*)(wsb + o); o += 256 * 256 * 2;
  unsigned short* wWth  = (unsigned short*)(wsb + o); o += 128 * 256 * 2;
  unsigned short* wWtl  = (unsigned short*)(wsb + o); o += 128 * 256 * 2;
  unsigned short* outWth = (unsigned short*)(wsb + o); o += 256 * 256 * 2;
  unsigned short* outWtl = (unsigned short*)(wsb + o); o += 256 * 256 * 2;
  float* offs    = (float*)(wsb + o); o += (size_t)N_Q * 256 * 4;
  float* wlog    = (float*)(wsb + o); o += (size_t)N_Q * 128 * 4;
  unsigned short* partial = (unsigned short*)(wsb + o);
  o += (size_t)N_CAM * N_Q * 256 * 2;                                      // 30.7 MB

  wprep_k<<<640, 256, 0, stream>>>(oW, wW, outW,
                                   oWth, oWtl, wWth, wWtl, outWth, outWtl);

  fused_prep_gemm_k<<<TRANS_BLKS + G12_BLKS, 256, 0, stream>>>(
      feats, query, ft, oWth, oWtl, ob, offs, wWth, wWtl, wb, wlog);

  sample_cam<<<N_CAM * (N_Q / 2), 256, 0, stream>>>(ft, offs, wlog, refp, mask,
                                                    partial);

  gemm_out_k<<<(N_Q + OUT_ROWS - 1) / OUT_ROWS, 256, 0, stream>>>(
      partial, mask, outWth, outWtl, outb, out);
}

// Round 15
// 141.664 us; speedup vs baseline: 1.2900x; 1.0205x over previous
//
#include <hip/hip_runtime.h>
#include <hip/hip_bf16.h>

#define N_Q   10000
#define N_CAM 6
#define HIMG  60
#define WIMG  100
#define NPIX  6000

typedef __attribute__((ext_vector_type(4))) float f32x4;
typedef __attribute__((ext_vector_type(2))) float f32x2;
typedef __attribute__((ext_vector_type(8))) short bf16x8;

__device__ __forceinline__ unsigned short f2bf(float x) {
  __hip_bfloat16 b = __float2bfloat16(x);
  return *reinterpret_cast<unsigned short*>(&b);
}
__device__ __forceinline__ float bf2f(unsigned short u) {
  return __uint_as_float(((unsigned)u) << 16);
}
__device__ __forceinline__ float bf16lo(unsigned int u) {
  return __uint_as_float(u << 16);
}
__device__ __forceinline__ float bf16hi(unsigned int u) {
  return __uint_as_float(u & 0xffff0000u);
}
// packed dual-FMA: acc = a * b + acc (2 channels per instruction)
__device__ __forceinline__ void pk_fma(f32x2& acc, f32x2 a, f32x2 b) {
  asm("v_pk_fma_f32 %0, %1, %2, %0" : "+v"(acc) : "v"(a), "v"(b));
}
// load 8 consecutive f32, split to bf16 hi/lo fragments in-register
__device__ __forceinline__ void split8(const float* pa, bf16x8& ah, bf16x8& al) {
  const float4 v0 = *reinterpret_cast<const float4*>(pa);
  const float4 v1 = *reinterpret_cast<const float4*>(pa + 4);
  const float v[8] = {v0.x, v0.y, v0.z, v0.w, v1.x, v1.y, v1.z, v1.w};
#pragma unroll
  for (int j = 0; j < 8; ++j) {
    const unsigned short hb = f2bf(v[j]);
    ah[j] = (short)hb;
    al[j] = (short)f2bf(v[j] - bf2f(hb));
  }
}

// ---------------------------------------------------------------------------
// Kernel 1 (tiny): weight transpose + hi/lo decompose. 640 blocks.
// ---------------------------------------------------------------------------
__global__ __launch_bounds__(256) void wprep_k(
    const float* __restrict__ oW, const float* __restrict__ wW,
    const float* __restrict__ outW,
    unsigned short* __restrict__ oWth,  unsigned short* __restrict__ oWtl,
    unsigned short* __restrict__ wWth,  unsigned short* __restrict__ wWtl,
    unsigned short* __restrict__ outWth,unsigned short* __restrict__ outWtl) {
  const int b = blockIdx.x, k = threadIdx.x;
  float v; unsigned short *dh, *dl; int idx;
  if (b < 256) {
    v = oW[k * 256 + b]; dh = oWth; dl = oWtl; idx = b * 256 + k;
  } else if (b < 384) {
    int nn = b - 256; v = wW[k * 128 + nn]; dh = wWth; dl = wWtl; idx = nn * 256 + k;
  } else {
    int nn = b - 384; v = outW[k * 256 + nn]; dh = outWth; dl = outWtl; idx = nn * 256 + k;
  }
  unsigned short hv = f2bf(v);
  dh[idx] = hv;
  dl[idx] = f2bf(v - bf2f(hv));
}

// ---------------------------------------------------------------------------
// MFMA GEMM body, A = f32 row-major split in-register; B pre-split bf16 hi/lo.
// mode 1: tanh(v)*0.12  2: exp(v)
// ---------------------------------------------------------------------------
__device__ __forceinline__ void gemm_bodyA32(
    const float* __restrict__ A,
    const unsigned short* __restrict__ Bh, const unsigned short* __restrict__ Bl,
    const float* __restrict__ bias, float* __restrict__ C,
    int M, int N, int mode, int bm, int bn, int tid) {
  const int l = tid & 63, w = tid >> 6;
  const int wm = w >> 1, wn = w & 1;
  const int lr = l & 15;
  const int lk = (l >> 4) * 8;

  const int am0 = min(bm + wm * 32 + lr, M - 1);
  const int am1 = min(bm + wm * 32 + 16 + lr, M - 1);
  const int bn0 = bn + wn * 32 + lr;
  const int bn1 = bn0 + 16;

  const float* pa0 = A + (size_t)am0 * 256 + lk;
  const float* pa1 = A + (size_t)am1 * 256 + lk;
  const bf16x8* pbh0 = (const bf16x8*)(Bh + (size_t)bn0 * 256 + lk);
  const bf16x8* pbh1 = (const bf16x8*)(Bh + (size_t)bn1 * 256 + lk);
  const bf16x8* pbl0 = (const bf16x8*)(Bl + (size_t)bn0 * 256 + lk);
  const bf16x8* pbl1 = (const bf16x8*)(Bl + (size_t)bn1 * 256 + lk);

  f32x4 acc00 = {}, acc01 = {}, acc10 = {}, acc11 = {};

#pragma unroll
  for (int ks = 0; ks < 8; ++ks) {
    bf16x8 ah0, al0, ah1, al1;
    split8(pa0 + ks * 32, ah0, al0);
    split8(pa1 + ks * 32, ah1, al1);
    bf16x8 bh0 = pbh0[ks * 4], bh1 = pbh1[ks * 4];
    bf16x8 bl0 = pbl0[ks * 4], bl1 = pbl1[ks * 4];
    acc00 = __builtin_amdgcn_mfma_f32_16x16x32_bf16(ah0, bh0, acc00, 0, 0, 0);
    acc00 = __builtin_amdgcn_mfma_f32_16x16x32_bf16(ah0, bl0, acc00, 0, 0, 0);
    acc00 = __builtin_amdgcn_mfma_f32_16x16x32_bf16(al0, bh0, acc00, 0, 0, 0);
    acc01 = __builtin_amdgcn_mfma_f32_16x16x32_bf16(ah0, bh1, acc01, 0, 0, 0);
    acc01 = __builtin_amdgcn_mfma_f32_16x16x32_bf16(ah0, bl1, acc01, 0, 0, 0);
    acc01 = __builtin_amdgcn_mfma_f32_16x16x32_bf16(al0, bh1, acc01, 0, 0, 0);
    acc10 = __builtin_amdgcn_mfma_f32_16x16x32_bf16(ah1, bh0, acc10, 0, 0, 0);
    acc10 = __builtin_amdgcn_mfma_f32_16x16x32_bf16(ah1, bl0, acc10, 0, 0, 0);
    acc10 = __builtin_amdgcn_mfma_f32_16x16x32_bf16(al1, bh0, acc10, 0, 0, 0);
    acc11 = __builtin_amdgcn_mfma_f32_16x16x32_bf16(ah1, bh1, acc11, 0, 0, 0);
    acc11 = __builtin_amdgcn_mfma_f32_16x16x32_bf16(ah1, bl1, acc11, 0, 0, 0);
    acc11 = __builtin_amdgcn_mfma_f32_16x16x32_bf16(al1, bh1, acc11, 0, 0, 0);
  }

  const float bias0 = bias[bn + wn * 32 + lr];
  const float bias1 = bias[bn + wn * 32 + 16 + lr];
  const int row0 = bm + wm * 32 + (l >> 4) * 4;
  const int col0 = bn + wn * 32 + lr;
#pragma unroll
  for (int r = 0; r < 4; ++r) {
    int rowA = row0 + r, rowB = row0 + 16 + r;
    float v00 = acc00[r] + bias0, v01 = acc01[r] + bias1;
    float v10 = acc10[r] + bias0, v11 = acc11[r] + bias1;
    if (mode == 1) {
      v00 = tanhf(v00) * 0.12f; v01 = tanhf(v01) * 0.12f;
      v10 = tanhf(v10) * 0.12f; v11 = tanhf(v11) * 0.12f;
    } else if (mode == 2) {
      v00 = __expf(v00); v01 = __expf(v01);
      v10 = __expf(v10); v11 = __expf(v11);
    }
    if (rowA < M) {
      C[(size_t)rowA * N + col0] = v00;
      C[(size_t)rowA * N + col0 + 16] = v01;
    }
    if (rowB < M) {
      C[(size_t)rowB * N + col0] = v10;
      C[(size_t)rowB * N + col0 + 16] = v11;
    }
  }
}

// ---------------------------------------------------------------------------
// Kernel 2 (fused): feats transpose (564 blocks) + offset/logit GEMMs
// (942 col-tile-major blocks, reading f32 query directly). r12 structure.
// ---------------------------------------------------------------------------
#define TRANS_BLKS (N_CAM * 94)
#define G12_BLKS   (157 * 6)

__global__ __launch_bounds__(256) void fused_prep_gemm_k(
    const float* __restrict__ in,   // image feats
    const float* __restrict__ q,    // f32 query
    unsigned short* __restrict__ ftout,
    const unsigned short* __restrict__ B1h, const unsigned short* __restrict__ B1l,
    const float* __restrict__ b1, float* __restrict__ C1,
    const unsigned short* __restrict__ B2h, const unsigned short* __restrict__ B2l,
    const float* __restrict__ b2, float* __restrict__ C2) {
  __shared__ float tile[64][65];
  const int tid = threadIdx.x;
  if (blockIdx.x < TRANS_BLKS) {
    const int cam = blockIdx.x / 94;
    const int px0 = (blockIdx.x % 94) * 64;
    const int lpx = tid & 63;
    const int cg  = tid >> 6;
    const int px  = px0 + lpx;
    const bool pv = px < NPIX;

    for (int c0 = 0; c0 < 256; c0 += 64) {
#pragma unroll
      for (int i = 0; i < 16; ++i) {
        int cc = cg * 16 + i;
        tile[lpx][cc] = pv ? in[(cam * 256 + c0 + cc) * NPIX + px] : 0.f;
      }
      __syncthreads();
      const int wc = tid & 63;
      const int pg = tid >> 6;
#pragma unroll
      for (int i = 0; i < 16; ++i) {
        int lp = pg * 16 + i;
        int gpx = px0 + lp;
        if (gpx < NPIX)
          ftout[(size_t)(cam * NPIX + gpx) * 256 + c0 + wc] = f2bf(tile[lp][wc]);
      }
      __syncthreads();
    }
    return;
  }
  const int b  = blockIdx.x - TRANS_BLKS;
  const int bt = b % 6;            // column tile; consecutive blocks share A
  const int bm = (b / 6) * 64;
  if (bt < 4)
    gemm_bodyA32(q, B1h, B1l, b1, C1, N_Q, 256, 1, bm, bt * 64, tid);
  else
    gemm_bodyA32(q, B2h, B2l, b2, C2, N_Q, 128, 2, bm, (bt - 4) * 64, tid);
}

// ---------------------------------------------------------------------------
// Kernel 3: per-cam deformable sampling. NEW: 128-thread blocks = ONE query
// x ONE cam (60000 blocks, 4.8 KB LDS) -> finer CU packing around early
// exits, up to 16 blocks/CU at the 32-wave cap. Chain/math identical to r8.
// ---------------------------------------------------------------------------
__global__ __launch_bounds__(128) void sample_cam(
    const unsigned short* __restrict__ ft, // (6,6000,256) bf16
    const float* __restrict__ offs,        // (N,256)
    const float* __restrict__ wlog,        // (N,128)  E=exp(logit)
    const float* __restrict__ refp,        // (6,N,4,2)
    const int*   __restrict__ mask,        // (6,N,4)
    unsigned short* __restrict__ partial) {// (6,N,256) bf16 raw sums
  const int t   = threadIdx.x;      // 0..127
  const int cam = blockIdx.x / N_Q;
  const int n   = blockIdx.x % N_Q;
  const int h   = t >> 4;
  const int p   = t & 15;          // phase-A point
  const int pp  = p >> 2;
  const int c   = (t >> 2) & 3;    // phase-B corner
  const int ch  = t & 3;           // phase-B channel chunk

  const int vis = mask[(cam * N_Q + n) * 4 + pp];
  const unsigned long long bal = __ballot(vis != 0);
  if (!(bal & 0x1111ULL)) return;  // query invisible in this cam

  __shared__ float lds[1216];
  unsigned int* ldsu = reinterpret_cast<unsigned int*>(lds);

  const float2 off = reinterpret_cast<const float2*>(offs)[n * 128 + t];
  const float E = wlog[n * 128 + t];
  const uint4* ftq2 = reinterpret_cast<const uint4*>(ft)
                      + (size_t)cam * (NPIX * 32) + (unsigned)(h * 4 + ch);

  const int abase = h * 152 + p * 9;
  const int rbase = h * 152;

  // masked softmax (pre-exponentiated): w = E*vis / sum(E*vis)
  float e = vis ? E : 0.f;
  float s = e;
#pragma unroll
  for (int m = 8; m >= 1; m >>= 1)
    s += __shfl_xor(s, m, 16);
  const float wgt = e / fmaxf(s, 1e-6f);

  // Phase A: this thread's point -> corner weights + pixel indices
  const float2 ref = reinterpret_cast<const float2*>(refp)[(cam * N_Q + n) * 4 + pp];
  const float x = fmaf(ref.x + off.x, (float)WIMG, -0.5f);
  const float y = fmaf(ref.y + off.y, (float)HIMG, -0.5f);
  const float x0f = floorf(x), y0f = floorf(y);
  const float wx = x - x0f, wy = y - y0f;
  const int x0 = (int)x0f, y0 = (int)y0f;
  const int x1 = x0 + 1, y1 = y0 + 1;
  const float mx0 = (x0 >= 0 && x0 < WIMG) ? 1.f : 0.f;
  const float mx1 = (x1 >= 0 && x1 < WIMG) ? 1.f : 0.f;
  const float my0 = (y0 >= 0 && y0 < HIMG) ? 1.f : 0.f;
  const float my1 = (y1 >= 0 && y1 < HIMG) ? 1.f : 0.f;
  const int xc0 = min(max(x0, 0), WIMG - 1);
  const int xc1 = min(max(x1, 0), WIMG - 1);
  const int yc0 = min(max(y0, 0), HIMG - 1);
  const int yc1 = min(max(y1, 0), HIMG - 1);
  lds[abase + 0] = (1.f - wx) * (1.f - wy) * mx0 * my0 * wgt;
  lds[abase + 1] = wx * (1.f - wy) * mx1 * my0 * wgt;
  lds[abase + 2] = (1.f - wx) * wy * mx0 * my1 * wgt;
  lds[abase + 3] = wx * wy * mx1 * my1 * wgt;
  ldsu[abase + 4] = (unsigned)(yc0 * WIMG + xc0);
  ldsu[abase + 5] = (unsigned)(yc0 * WIMG + xc1);
  ldsu[abase + 6] = (unsigned)(yc1 * WIMG + xc0);
  ldsu[abase + 7] = (unsigned)(yc1 * WIMG + xc1);
  __builtin_amdgcn_wave_barrier();

  // Phase B: issue ALL visible pillars' uint4 gathers, then consume (packed).
  f32x2 acc2[4] = {{0.f, 0.f}, {0.f, 0.f}, {0.f, 0.f}, {0.f, 0.f}};
  const bool pv0 = (bal      ) & 1ULL;
  const bool pv1 = (bal >>  4) & 1ULL;
  const bool pv2 = (bal >>  8) & 1ULL;
  const bool pv3 = (bal >> 12) & 1ULL;
  uint4 u0[4], u1[4], u2[4], u3[4];

#define ISSUE(U, P)                                                          \
  if (pv##P) {                                                               \
    _Pragma("unroll")                                                        \
    for (int pn = 0; pn < 4; ++pn) {                                         \
      const unsigned pix = ldsu[rbase + ((P) * 4 + pn) * 9 + 4 + c];         \
      U[pn] = ftq2[pix * 32u];                                               \
    }                                                                        \
  }
  ISSUE(u0, 0) ISSUE(u1, 1) ISSUE(u2, 2) ISSUE(u3, 3)

#define CONSUME(U, P)                                                        \
  if (pv##P) {                                                               \
    _Pragma("unroll")                                                        \
    for (int pn = 0; pn < 4; ++pn) {                                         \
      const float wv = lds[rbase + ((P) * 4 + pn) * 9 + c];                  \
      const f32x2 w2 = {wv, wv};                                             \
      f32x2 a;                                                               \
      a.x = bf16lo(U[pn].x); a.y = __uint_as_float(U[pn].x);                 \
      pk_fma(acc2[0], a, w2);                                                \
      a.x = bf16lo(U[pn].y); a.y = __uint_as_float(U[pn].y);                 \
      pk_fma(acc2[1], a, w2);                                                \
      a.x = bf16lo(U[pn].z); a.y = __uint_as_float(U[pn].z);                 \
      pk_fma(acc2[2], a, w2);                                                \
      a.x = bf16lo(U[pn].w); a.y = __uint_as_float(U[pn].w);                 \
      pk_fma(acc2[3], a, w2);                                                \
    }                                                                        \
  }
  CONSUME(u0, 0) CONSUME(u1, 1) CONSUME(u2, 2) CONSUME(u3, 3)
#undef ISSUE
#undef CONSUME

  float acc[8];
#pragma unroll
  for (int j = 0; j < 4; ++j) { acc[2 * j] = acc2[j].x; acc[2 * j + 1] = acc2[j].y; }
  // reduce over the 4 corner lanes (bits 2-3 of lane id)
#pragma unroll
  for (int j = 0; j < 8; ++j) acc[j] += __shfl_xor(acc[j], 4);
#pragma unroll
  for (int j = 0; j < 8; ++j) acc[j] += __shfl_xor(acc[j], 8);

  if (c == 0) {
    unsigned w01 = (unsigned)f2bf(acc[0]) | ((unsigned)f2bf(acc[1]) << 16);
    unsigned w23 = (unsigned)f2bf(acc[2]) | ((unsigned)f2bf(acc[3]) << 16);
    unsigned w45 = (unsigned)f2bf(acc[4]) | ((unsigned)f2bf(acc[5]) << 16);
    unsigned w67 = (unsigned)f2bf(acc[6]) | ((unsigned)f2bf(acc[7]) << 16);
    uint4 v = {w01, w23, w45, w67};
    reinterpret_cast<uint4*>(partial)[((size_t)cam * N_Q + n) * 32 + h * 4 + ch] = v;
  }
}

// ---------------------------------------------------------------------------
// Kernel 4: out-projection GEMM with FUSED cam-combine, one block per 32-row
// m-tile (313 blocks, 33.8 KB LDS -> 2 blocks/CU).
// ---------------------------------------------------------------------------
#define OUT_ROWS 32

__global__ __launch_bounds__(256) void gemm_out_k(
    const unsigned short* __restrict__ partial, // (6,N,256) bf16 raw sums
    const int*   __restrict__ mask,             // (6,N,4)
    const unsigned short* __restrict__ Bh, const unsigned short* __restrict__ Bl,
    const float* __restrict__ bias, float* __restrict__ C) {
  __shared__ unsigned short Ahs[OUT_ROWS][264];
  __shared__ unsigned short Als[OUT_ROWS][264];
  __shared__ float    sinv[OUT_ROWS];
  __shared__ unsigned sbits[OUT_ROWS];

  const int tid = threadIdx.x;
  const int bm  = blockIdx.x * OUT_ROWS;

  // per-row visibility summary
  if (tid < OUT_ROWS) {
    const int n = min(bm + tid, N_Q - 1);
    unsigned bits = 0; int cnt = 0;
#pragma unroll
    for (int cam = 0; cam < N_CAM; ++cam) {
      const int4 m4 = *reinterpret_cast<const int4*>(&mask[(cam * N_Q + n) * 4]);
      const int any = (m4.x | m4.y | m4.z | m4.w) ? 1 : 0;
      bits |= (unsigned)any << cam;
      cnt += any;
    }
    sbits[tid] = bits;
    sinv[tid]  = (cnt > 0) ? (1.f / (float)cnt) : 1.f;
  }
  __syncthreads();

  // combine: 1024 units (row, slot-of-8-channels); 4 units per thread.
  const uint4* pq = reinterpret_cast<const uint4*>(partial);
#pragma unroll
  for (int i = 0; i < 4; ++i) {
    const int u    = tid + i * 256;
    const int row  = u >> 5;
    const int slot = u & 31;
    const int n    = min(bm + row, N_Q - 1);
    const unsigned bits = sbits[row];
    const float    inv  = sinv[row];
    float v[8] = {0.f, 0.f, 0.f, 0.f, 0.f, 0.f, 0.f, 0.f};
#pragma unroll
    for (int cam = 0; cam < N_CAM; ++cam) {
      if ((bits >> cam) & 1u) {
        const uint4 x = pq[((size_t)cam * N_Q + n) * 32 + slot];
        v[0] += bf16lo(x.x); v[1] += bf16hi(x.x);
        v[2] += bf16lo(x.y); v[3] += bf16hi(x.y);
        v[4] += bf16lo(x.z); v[5] += bf16hi(x.z);
        v[6] += bf16lo(x.w); v[7] += bf16hi(x.w);
      }
    }
    unsigned short hh[8], ll[8];
#pragma unroll
    for (int j = 0; j < 8; ++j) {
      const float x = v[j] * inv;
      hh[j] = f2bf(x);
      ll[j] = f2bf(x - bf2f(hh[j]));
    }
    uint4 ph = {(unsigned)hh[0] | ((unsigned)hh[1] << 16),
                (unsigned)hh[2] | ((unsigned)hh[3] << 16),
                (unsigned)hh[4] | ((unsigned)hh[5] << 16),
                (unsigned)hh[6] | ((unsigned)hh[7] << 16)};
    uint4 pl = {(unsigned)ll[0] | ((unsigned)ll[1] << 16),
                (unsigned)ll[2] | ((unsigned)ll[3] << 16),
                (unsigned)ll[4] | ((unsigned)ll[5] << 16),
                (unsigned)ll[6] | ((unsigned)ll[7] << 16)};
    *reinterpret_cast<uint4*>(&Ahs[row][slot * 8]) = ph;
    *reinterpret_cast<uint4*>(&Als[row][slot * 8]) = pl;
  }
  __syncthreads();

  // GEMM: wave w -> cols [w*64, w*64+64); 2 row-frags x 4 col-frags.
  const int l  = tid & 63;
  const int w  = tid >> 6;
  const int lr = l & 15;
  const int lk = (l >> 4) * 8;

  const bf16x8* pbh[4];
  const bf16x8* pbl[4];
#pragma unroll
  for (int cf = 0; cf < 4; ++cf) {
    const int col = w * 64 + cf * 16 + lr;
    pbh[cf] = (const bf16x8*)(Bh + (size_t)col * 256 + lk);
    pbl[cf] = (const bf16x8*)(Bl + (size_t)col * 256 + lk);
  }

  f32x4 acc[2][4] = {};

#pragma unroll
  for (int ks = 0; ks < 8; ++ks) {
    bf16x8 ah[2], al[2], bh[4], bl[4];
#pragma unroll
    for (int rf = 0; rf < 2; ++rf) {
      ah[rf] = *reinterpret_cast<const bf16x8*>(&Ahs[rf * 16 + lr][ks * 32 + lk]);
      al[rf] = *reinterpret_cast<const bf16x8*>(&Als[rf * 16 + lr][ks * 32 + lk]);
    }
#pragma unroll
    for (int cf = 0; cf < 4; ++cf) {
      bh[cf] = pbh[cf][ks * 4];
      bl[cf] = pbl[cf][ks * 4];
    }
#pragma unroll
    for (int rf = 0; rf < 2; ++rf)
#pragma unroll
      for (int cf = 0; cf < 4; ++cf) {
        acc[rf][cf] = __builtin_amdgcn_mfma_f32_16x16x32_bf16(ah[rf], bh[cf], acc[rf][cf], 0, 0, 0);
        acc[rf][cf] = __builtin_amdgcn_mfma_f32_16x16x32_bf16(ah[rf], bl[cf], acc[rf][cf], 0, 0, 0);
        acc[rf][cf] = __builtin_amdgcn_mfma_f32_16x16x32_bf16(al[rf], bh[cf], acc[rf][cf], 0, 0, 0);
      }
  }

  float bias_cf[4];
#pragma unroll
  for (int cf = 0; cf < 4; ++cf) bias_cf[cf] = bias[w * 64 + cf * 16 + lr];

#pragma unroll
  for (int rf = 0; rf < 2; ++rf) {
    const int row0 = bm + rf * 16 + (l >> 4) * 4;
#pragma unroll
    for (int r = 0; r < 4; ++r) {
      const int row = row0 + r;
      if (row < N_Q) {
#pragma unroll
        for (int cf = 0; cf < 4; ++cf) {
          const int col = w * 64 + cf * 16 + lr;
          C[(size_t)row * 256 + col] = acc[rf][cf][r] + bias_cf[cf];
        }
      }
    }
  }
}

// ---------------------------------------------------------------------------
extern "C" void kernel_launch(void* const* d_in, const int* in_sizes, int n_in,
                              void* d_out, int out_size, void* d_ws, size_t ws_size,
                              hipStream_t stream) {
  const float* query = (const float*)d_in[0];
  const float* feats = (const float*)d_in[1];
  const float* refp  = (const float*)d_in[2];
  const int*   mask  = (const int*)d_in[3];
  const float* oW    = (const float*)d_in[4];
  const float* ob    = (const float*)d_in[5];
  const float* wW    = (const float*)d_in[6];
  const float* wb    = (const float*)d_in[7];
  const float* outW  = (const float*)d_in[8];
  const float* outb  = (const float*)d_in[9];
  float* out = (float*)d_out;

  char* wsb = (char*)d_ws;
  size_t o = 0;
  unsigned short* ft = (unsigned short*)(wsb + o); o += (size_t)N_CAM * NPIX * 256 * 2;
  unsigned short* oWth  = (unsigned short*)(wsb + o); o += 256 * 256 * 2;
  unsigned short* oWtl  = (unsigned short*)(wsb + o); o += 256 * 256 * 2;
  unsigned short* wWth  = (unsigned short*)(wsb + o); o += 128 * 256 * 2;
  unsigned short* wWtl  = (unsigned short*)(wsb + o); o += 128 * 256 * 2;
  unsigned short* outWth = (unsigned short*)(wsb + o); o += 256 * 256 * 2;
  unsigned short* outWtl = (unsigned short*)(wsb + o); o += 256 * 256 * 2;
  float* offs    = (float*)(wsb + o); o += (size_t)N_Q * 256 * 4;
  float* wlog    = (float*)(wsb + o); o += (size_t)N_Q * 128 * 4;
  unsigned short* partial = (unsigned short*)(wsb + o);
  o += (size_t)N_CAM * N_Q * 256 * 2;                                      // 30.7 MB

  wprep_k<<<640, 256, 0, stream>>>(oW, wW, outW,
                                   oWth, oWtl, wWth, wWtl, outWth, outWtl);

  fused_prep_gemm_k<<<TRANS_BLKS + G12_BLKS, 256, 0, stream>>>(
      feats, query, ft, oWth, oWtl, ob, offs, wWth, wWtl, wb, wlog);

  sample_cam<<<N_CAM * N_Q, 128, 0, stream>>>(ft, offs, wlog, refp, mask,
                                              partial);

  gemm_out_k<<<(N_Q + OUT_ROWS - 1) / OUT_ROWS, 256, 0, stream>>>(
      partial, mask, outWth, outWtl, outb, out);
}

// Round 16
// 140.571 us; speedup vs baseline: 1.3001x; 1.0078x over previous
//
#include <hip/hip_runtime.h>
#include <hip/hip_bf16.h>

#define N_Q   10000
#define N_CAM 6
#define HIMG  60
#define WIMG  100
#define NPIX  6000

typedef __attribute__((ext_vector_type(4))) float f32x4;
typedef __attribute__((ext_vector_type(2))) float f32x2;
typedef __attribute__((ext_vector_type(8))) short bf16x8;

__device__ __forceinline__ unsigned short f2bf(float x) {
  __hip_bfloat16 b = __float2bfloat16(x);
  return *reinterpret_cast<unsigned short*>(&b);
}
__device__ __forceinline__ float bf2f(unsigned short u) {
  return __uint_as_float(((unsigned)u) << 16);
}
__device__ __forceinline__ float bf16lo(unsigned int u) {
  return __uint_as_float(u << 16);
}
__device__ __forceinline__ float bf16hi(unsigned int u) {
  return __uint_as_float(u & 0xffff0000u);
}
// packed dual-FMA: acc = a * b + acc (2 channels per instruction)
__device__ __forceinline__ void pk_fma(f32x2& acc, f32x2 a, f32x2 b) {
  asm("v_pk_fma_f32 %0, %1, %2, %0" : "+v"(acc) : "v"(a), "v"(b));
}
// load 8 consecutive f32, split to bf16 hi/lo fragments in-register
__device__ __forceinline__ void split8(const float* pa, bf16x8& ah, bf16x8& al) {
  const float4 v0 = *reinterpret_cast<const float4*>(pa);
  const float4 v1 = *reinterpret_cast<const float4*>(pa + 4);
  const float v[8] = {v0.x, v0.y, v0.z, v0.w, v1.x, v1.y, v1.z, v1.w};
#pragma unroll
  for (int j = 0; j < 8; ++j) {
    const unsigned short hb = f2bf(v[j]);
    ah[j] = (short)hb;
    al[j] = (short)f2bf(v[j] - bf2f(hb));
  }
}

// ---------------------------------------------------------------------------
// Kernel 1 (tiny): weight transpose + hi/lo decompose. 640 blocks.
// ---------------------------------------------------------------------------
__global__ __launch_bounds__(256) void wprep_k(
    const float* __restrict__ oW, const float* __restrict__ wW,
    const float* __restrict__ outW,
    unsigned short* __restrict__ oWth,  unsigned short* __restrict__ oWtl,
    unsigned short* __restrict__ wWth,  unsigned short* __restrict__ wWtl,
    unsigned short* __restrict__ outWth,unsigned short* __restrict__ outWtl) {
  const int b = blockIdx.x, k = threadIdx.x;
  float v; unsigned short *dh, *dl; int idx;
  if (b < 256) {
    v = oW[k * 256 + b]; dh = oWth; dl = oWtl; idx = b * 256 + k;
  } else if (b < 384) {
    int nn = b - 256; v = wW[k * 128 + nn]; dh = wWth; dl = wWtl; idx = nn * 256 + k;
  } else {
    int nn = b - 384; v = outW[k * 256 + nn]; dh = outWth; dl = outWtl; idx = nn * 256 + k;
  }
  unsigned short hv = f2bf(v);
  dh[idx] = hv;
  dl[idx] = f2bf(v - bf2f(hv));
}

// ---------------------------------------------------------------------------
// MFMA GEMM body, A = f32 row-major split in-register; B pre-split bf16 hi/lo.
// mode 1: tanh(v)*0.12  2: exp(v)
// ---------------------------------------------------------------------------
__device__ __forceinline__ void gemm_bodyA32(
    const float* __restrict__ A,
    const unsigned short* __restrict__ Bh, const unsigned short* __restrict__ Bl,
    const float* __restrict__ bias, float* __restrict__ C,
    int M, int N, int mode, int bm, int bn, int tid) {
  const int l = tid & 63, w = tid >> 6;
  const int wm = w >> 1, wn = w & 1;
  const int lr = l & 15;
  const int lk = (l >> 4) * 8;

  const int am0 = min(bm + wm * 32 + lr, M - 1);
  const int am1 = min(bm + wm * 32 + 16 + lr, M - 1);
  const int bn0 = bn + wn * 32 + lr;
  const int bn1 = bn0 + 16;

  const float* pa0 = A + (size_t)am0 * 256 + lk;
  const float* pa1 = A + (size_t)am1 * 256 + lk;
  const bf16x8* pbh0 = (const bf16x8*)(Bh + (size_t)bn0 * 256 + lk);
  const bf16x8* pbh1 = (const bf16x8*)(Bh + (size_t)bn1 * 256 + lk);
  const bf16x8* pbl0 = (const bf16x8*)(Bl + (size_t)bn0 * 256 + lk);
  const bf16x8* pbl1 = (const bf16x8*)(Bl + (size_t)bn1 * 256 + lk);

  f32x4 acc00 = {}, acc01 = {}, acc10 = {}, acc11 = {};

#pragma unroll
  for (int ks = 0; ks < 8; ++ks) {
    bf16x8 ah0, al0, ah1, al1;
    split8(pa0 + ks * 32, ah0, al0);
    split8(pa1 + ks * 32, ah1, al1);
    bf16x8 bh0 = pbh0[ks * 4], bh1 = pbh1[ks * 4];
    bf16x8 bl0 = pbl0[ks * 4], bl1 = pbl1[ks * 4];
    acc00 = __builtin_amdgcn_mfma_f32_16x16x32_bf16(ah0, bh0, acc00, 0, 0, 0);
    acc00 = __builtin_amdgcn_mfma_f32_16x16x32_bf16(ah0, bl0, acc00, 0, 0, 0);
    acc00 = __builtin_amdgcn_mfma_f32_16x16x32_bf16(al0, bh0, acc00, 0, 0, 0);
    acc01 = __builtin_amdgcn_mfma_f32_16x16x32_bf16(ah0, bh1, acc01, 0, 0, 0);
    acc01 = __builtin_amdgcn_mfma_f32_16x16x32_bf16(ah0, bl1, acc01, 0, 0, 0);
    acc01 = __builtin_amdgcn_mfma_f32_16x16x32_bf16(al0, bh1, acc01, 0, 0, 0);
    acc10 = __builtin_amdgcn_mfma_f32_16x16x32_bf16(ah1, bh0, acc10, 0, 0, 0);
    acc10 = __builtin_amdgcn_mfma_f32_16x16x32_bf16(ah1, bl0, acc10, 0, 0, 0);
    acc10 = __builtin_amdgcn_mfma_f32_16x16x32_bf16(al1, bh0, acc10, 0, 0, 0);
    acc11 = __builtin_amdgcn_mfma_f32_16x16x32_bf16(ah1, bh1, acc11, 0, 0, 0);
    acc11 = __builtin_amdgcn_mfma_f32_16x16x32_bf16(ah1, bl1, acc11, 0, 0, 0);
    acc11 = __builtin_amdgcn_mfma_f32_16x16x32_bf16(al1, bh1, acc11, 0, 0, 0);
  }

  const float bias0 = bias[bn + wn * 32 + lr];
  const float bias1 = bias[bn + wn * 32 + 16 + lr];
  const int row0 = bm + wm * 32 + (l >> 4) * 4;
  const int col0 = bn + wn * 32 + lr;
#pragma unroll
  for (int r = 0; r < 4; ++r) {
    int rowA = row0 + r, rowB = row0 + 16 + r;
    float v00 = acc00[r] + bias0, v01 = acc01[r] + bias1;
    float v10 = acc10[r] + bias0, v11 = acc11[r] + bias1;
    if (mode == 1) {
      v00 = tanhf(v00) * 0.12f; v01 = tanhf(v01) * 0.12f;
      v10 = tanhf(v10) * 0.12f; v11 = tanhf(v11) * 0.12f;
    } else if (mode == 2) {
      v00 = __expf(v00); v01 = __expf(v01);
      v10 = __expf(v10); v11 = __expf(v11);
    }
    if (rowA < M) {
      C[(size_t)rowA * N + col0] = v00;
      C[(size_t)rowA * N + col0 + 16] = v01;
    }
    if (rowB < M) {
      C[(size_t)rowB * N + col0] = v10;
      C[(size_t)rowB * N + col0 + 16] = v11;
    }
  }
}

// ---------------------------------------------------------------------------
// Kernel 2 (fused): feats transpose (564 blocks) + offset/logit GEMMs
// (942 col-tile-major blocks, reading f32 query directly). r12 structure.
// ---------------------------------------------------------------------------
#define TRANS_BLKS (N_CAM * 94)
#define G12_BLKS   (157 * 6)

__global__ __launch_bounds__(256) void fused_prep_gemm_k(
    const float* __restrict__ in,   // image feats
    const float* __restrict__ q,    // f32 query
    unsigned short* __restrict__ ftout,
    const unsigned short* __restrict__ B1h, const unsigned short* __restrict__ B1l,
    const float* __restrict__ b1, float* __restrict__ C1,
    const unsigned short* __restrict__ B2h, const unsigned short* __restrict__ B2l,
    const float* __restrict__ b2, float* __restrict__ C2) {
  __shared__ float tile[64][65];
  const int tid = threadIdx.x;
  if (blockIdx.x < TRANS_BLKS) {
    const int cam = blockIdx.x / 94;
    const int px0 = (blockIdx.x % 94) * 64;
    const int lpx = tid & 63;
    const int cg  = tid >> 6;
    const int px  = px0 + lpx;
    const bool pv = px < NPIX;

    for (int c0 = 0; c0 < 256; c0 += 64) {
#pragma unroll
      for (int i = 0; i < 16; ++i) {
        int cc = cg * 16 + i;
        tile[lpx][cc] = pv ? in[(cam * 256 + c0 + cc) * NPIX + px] : 0.f;
      }
      __syncthreads();
      const int wc = tid & 63;
      const int pg = tid >> 6;
#pragma unroll
      for (int i = 0; i < 16; ++i) {
        int lp = pg * 16 + i;
        int gpx = px0 + lp;
        if (gpx < NPIX)
          ftout[(size_t)(cam * NPIX + gpx) * 256 + c0 + wc] = f2bf(tile[lp][wc]);
      }
      __syncthreads();
    }
    return;
  }
  const int b  = blockIdx.x - TRANS_BLKS;
  const int bt = b % 6;            // column tile; consecutive blocks share A
  const int bm = (b / 6) * 64;
  if (bt < 4)
    gemm_bodyA32(q, B1h, B1l, b1, C1, N_Q, 256, 1, bm, bt * 64, tid);
  else
    gemm_bodyA32(q, B2h, B2l, b2, C2, N_Q, 128, 2, bm, (bt - 4) * 64, tid);
}

// ---------------------------------------------------------------------------
// Kernel 3: per-cam deformable sampling, 128-thread blocks (1 query x 1 cam).
// NEW: XCD-aware block swizzle — with round-robin dispatch (block b -> XCD
// b%8), each XCD owns a contiguous 1250-query slice for ALL cams, so its
// offs/wlog working set (1.9 MB) stays L2-resident across cams.
// ---------------------------------------------------------------------------
__global__ __launch_bounds__(128) void sample_cam(
    const unsigned short* __restrict__ ft, // (6,6000,256) bf16
    const float* __restrict__ offs,        // (N,256)
    const float* __restrict__ wlog,        // (N,128)  E=exp(logit)
    const float* __restrict__ refp,        // (6,N,4,2)
    const int*   __restrict__ mask,        // (6,N,4)
    unsigned short* __restrict__ partial) {// (6,N,256) bf16 raw sums
  const int t    = threadIdx.x;     // 0..127
  // bijective swizzle: bid -> (xcd, slot) -> (cam, n)
  const int bid  = blockIdx.x;           // 0..59999
  const int xcd  = bid & 7;
  const int slot = bid >> 3;             // 0..7499
  const int cam  = slot / (N_Q / 8);     // 0..5  (N_Q/8 = 1250)
  const int n    = xcd * (N_Q / 8) + (slot % (N_Q / 8));
  const int h   = t >> 4;
  const int p   = t & 15;          // phase-A point
  const int pp  = p >> 2;
  const int c   = (t >> 2) & 3;    // phase-B corner
  const int ch  = t & 3;           // phase-B channel chunk

  const int vis = mask[(cam * N_Q + n) * 4 + pp];
  const unsigned long long bal = __ballot(vis != 0);
  if (!(bal & 0x1111ULL)) return;  // query invisible in this cam

  __shared__ float lds[1216];
  unsigned int* ldsu = reinterpret_cast<unsigned int*>(lds);

  const float2 off = reinterpret_cast<const float2*>(offs)[n * 128 + t];
  const float E = wlog[n * 128 + t];
  const uint4* ftq2 = reinterpret_cast<const uint4*>(ft)
                      + (size_t)cam * (NPIX * 32) + (unsigned)(h * 4 + ch);

  const int abase = h * 152 + p * 9;
  const int rbase = h * 152;

  // masked softmax (pre-exponentiated): w = E*vis / sum(E*vis)
  float e = vis ? E : 0.f;
  float s = e;
#pragma unroll
  for (int m = 8; m >= 1; m >>= 1)
    s += __shfl_xor(s, m, 16);
  const float wgt = e / fmaxf(s, 1e-6f);

  // Phase A: this thread's point -> corner weights + pixel indices
  const float2 ref = reinterpret_cast<const float2*>(refp)[(cam * N_Q + n) * 4 + pp];
  const float x = fmaf(ref.x + off.x, (float)WIMG, -0.5f);
  const float y = fmaf(ref.y + off.y, (float)HIMG, -0.5f);
  const float x0f = floorf(x), y0f = floorf(y);
  const float wx = x - x0f, wy = y - y0f;
  const int x0 = (int)x0f, y0 = (int)y0f;
  const int x1 = x0 + 1, y1 = y0 + 1;
  const float mx0 = (x0 >= 0 && x0 < WIMG) ? 1.f : 0.f;
  const float mx1 = (x1 >= 0 && x1 < WIMG) ? 1.f : 0.f;
  const float my0 = (y0 >= 0 && y0 < HIMG) ? 1.f : 0.f;
  const float my1 = (y1 >= 0 && y1 < HIMG) ? 1.f : 0.f;
  const int xc0 = min(max(x0, 0), WIMG - 1);
  const int xc1 = min(max(x1, 0), WIMG - 1);
  const int yc0 = min(max(y0, 0), HIMG - 1);
  const int yc1 = min(max(y1, 0), HIMG - 1);
  lds[abase + 0] = (1.f - wx) * (1.f - wy) * mx0 * my0 * wgt;
  lds[abase + 1] = wx * (1.f - wy) * mx1 * my0 * wgt;
  lds[abase + 2] = (1.f - wx) * wy * mx0 * my1 * wgt;
  lds[abase + 3] = wx * wy * mx1 * my1 * wgt;
  ldsu[abase + 4] = (unsigned)(yc0 * WIMG + xc0);
  ldsu[abase + 5] = (unsigned)(yc0 * WIMG + xc1);
  ldsu[abase + 6] = (unsigned)(yc1 * WIMG + xc0);
  ldsu[abase + 7] = (unsigned)(yc1 * WIMG + xc1);
  __builtin_amdgcn_wave_barrier();

  // Phase B: issue ALL visible pillars' uint4 gathers, then consume (packed).
  f32x2 acc2[4] = {{0.f, 0.f}, {0.f, 0.f}, {0.f, 0.f}, {0.f, 0.f}};
  const bool pv0 = (bal      ) & 1ULL;
  const bool pv1 = (bal >>  4) & 1ULL;
  const bool pv2 = (bal >>  8) & 1ULL;
  const bool pv3 = (bal >> 12) & 1ULL;
  uint4 u0[4], u1[4], u2[4], u3[4];

#define ISSUE(U, P)                                                          \
  if (pv##P) {                                                               \
    _Pragma("unroll")                                                        \
    for (int pn = 0; pn < 4; ++pn) {                                         \
      const unsigned pix = ldsu[rbase + ((P) * 4 + pn) * 9 + 4 + c];         \
      U[pn] = ftq2[pix * 32u];                                               \
    }                                                                        \
  }
  ISSUE(u0, 0) ISSUE(u1, 1) ISSUE(u2, 2) ISSUE(u3, 3)

#define CONSUME(U, P)                                                        \
  if (pv##P) {                                                               \
    _Pragma("unroll")                                                        \
    for (int pn = 0; pn < 4; ++pn) {                                         \
      const float wv = lds[rbase + ((P) * 4 + pn) * 9 + c];                  \
      const f32x2 w2 = {wv, wv};                                             \
      f32x2 a;                                                               \
      a.x = bf16lo(U[pn].x); a.y = __uint_as_float(U[pn].x);                 \
      pk_fma(acc2[0], a, w2);                                                \
      a.x = bf16lo(U[pn].y); a.y = __uint_as_float(U[pn].y);                 \
      pk_fma(acc2[1], a, w2);                                                \
      a.x = bf16lo(U[pn].z); a.y = __uint_as_float(U[pn].z);                 \
      pk_fma(acc2[2], a, w2);                                                \
      a.x = bf16lo(U[pn].w); a.y = __uint_as_float(U[pn].w);                 \
      pk_fma(acc2[3], a, w2);                                                \
    }                                                                        \
  }
  CONSUME(u0, 0) CONSUME(u1, 1) CONSUME(u2, 2) CONSUME(u3, 3)
#undef ISSUE
#undef CONSUME

  float acc[8];
#pragma unroll
  for (int j = 0; j < 4; ++j) { acc[2 * j] = acc2[j].x; acc[2 * j + 1] = acc2[j].y; }
  // reduce over the 4 corner lanes (bits 2-3 of lane id)
#pragma unroll
  for (int j = 0; j < 8; ++j) acc[j] += __shfl_xor(acc[j], 4);
#pragma unroll
  for (int j = 0; j < 8; ++j) acc[j] += __shfl_xor(acc[j], 8);

  if (c == 0) {
    unsigned w01 = (unsigned)f2bf(acc[0]) | ((unsigned)f2bf(acc[1]) << 16);
    unsigned w23 = (unsigned)f2bf(acc[2]) | ((unsigned)f2bf(acc[3]) << 16);
    unsigned w45 = (unsigned)f2bf(acc[4]) | ((unsigned)f2bf(acc[5]) << 16);
    unsigned w67 = (unsigned)f2bf(acc[6]) | ((unsigned)f2bf(acc[7]) << 16);
    uint4 v = {w01, w23, w45, w67};
    reinterpret_cast<uint4*>(partial)[((size_t)cam * N_Q + n) * 32 + h * 4 + ch] = v;
  }
}

// ---------------------------------------------------------------------------
// Kernel 4: out-projection GEMM with FUSED cam-combine, one block per 32-row
// m-tile (313 blocks, 33.8 KB LDS -> 2 blocks/CU).
// ---------------------------------------------------------------------------
#define OUT_ROWS 32

__global__ __launch_bounds__(256) void gemm_out_k(
    const unsigned short* __restrict__ partial, // (6,N,256) bf16 raw sums
    const int*   __restrict__ mask,             // (6,N,4)
    const unsigned short* __restrict__ Bh, const unsigned short* __restrict__ Bl,
    const float* __restrict__ bias, float* __restrict__ C) {
  __shared__ unsigned short Ahs[OUT_ROWS][264];
  __shared__ unsigned short Als[OUT_ROWS][264];
  __shared__ float    sinv[OUT_ROWS];
  __shared__ unsigned sbits[OUT_ROWS];

  const int tid = threadIdx.x;
  const int bm  = blockIdx.x * OUT_ROWS;

  // per-row visibility summary
  if (tid < OUT_ROWS) {
    const int n = min(bm + tid, N_Q - 1);
    unsigned bits = 0; int cnt = 0;
#pragma unroll
    for (int cam = 0; cam < N_CAM; ++cam) {
      const int4 m4 = *reinterpret_cast<const int4*>(&mask[(cam * N_Q + n) * 4]);
      const int any = (m4.x | m4.y | m4.z | m4.w) ? 1 : 0;
      bits |= (unsigned)any << cam;
      cnt += any;
    }
    sbits[tid] = bits;
    sinv[tid]  = (cnt > 0) ? (1.f / (float)cnt) : 1.f;
  }
  __syncthreads();

  // combine: 1024 units (row, slot-of-8-channels); 4 units per thread.
  const uint4* pq = reinterpret_cast<const uint4*>(partial);
#pragma unroll
  for (int i = 0; i < 4; ++i) {
    const int u    = tid + i * 256;
    const int row  = u >> 5;
    const int slot = u & 31;
    const int n    = min(bm + row, N_Q - 1);
    const unsigned bits = sbits[row];
    const float    inv  = sinv[row];
    float v[8] = {0.f, 0.f, 0.f, 0.f, 0.f, 0.f, 0.f, 0.f};
#pragma unroll
    for (int cam = 0; cam < N_CAM; ++cam) {
      if ((bits >> cam) & 1u) {
        const uint4 x = pq[((size_t)cam * N_Q + n) * 32 + slot];
        v[0] += bf16lo(x.x); v[1] += bf16hi(x.x);
        v[2] += bf16lo(x.y); v[3] += bf16hi(x.y);
        v[4] += bf16lo(x.z); v[5] += bf16hi(x.z);
        v[6] += bf16lo(x.w); v[7] += bf16hi(x.w);
      }
    }
    unsigned short hh[8], ll[8];
#pragma unroll
    for (int j = 0; j < 8; ++j) {
      const float x = v[j] * inv;
      hh[j] = f2bf(x);
      ll[j] = f2bf(x - bf2f(hh[j]));
    }
    uint4 ph = {(unsigned)hh[0] | ((unsigned)hh[1] << 16),
                (unsigned)hh[2] | ((unsigned)hh[3] << 16),
                (unsigned)hh[4] | ((unsigned)hh[5] << 16),
                (unsigned)hh[6] | ((unsigned)hh[7] << 16)};
    uint4 pl = {(unsigned)ll[0] | ((unsigned)ll[1] << 16),
                (unsigned)ll[2] | ((unsigned)ll[3] << 16),
                (unsigned)ll[4] | ((unsigned)ll[5] << 16),
                (unsigned)ll[6] | ((unsigned)ll[7] << 16)};
    *reinterpret_cast<uint4*>(&Ahs[row][slot * 8]) = ph;
    *reinterpret_cast<uint4*>(&Als[row][slot * 8]) = pl;
  }
  __syncthreads();

  // GEMM: wave w -> cols [w*64, w*64+64); 2 row-frags x 4 col-frags.
  const int l  = tid & 63;
  const int w  = tid >> 6;
  const int lr = l & 15;
  const int lk = (l >> 4) * 8;

  const bf16x8* pbh[4];
  const bf16x8* pbl[4];
#pragma unroll
  for (int cf = 0; cf < 4; ++cf) {
    const int col = w * 64 + cf * 16 + lr;
    pbh[cf] = (const bf16x8*)(Bh + (size_t)col * 256 + lk);
    pbl[cf] = (const bf16x8*)(Bl + (size_t)col * 256 + lk);
  }

  f32x4 acc[2][4] = {};

#pragma unroll
  for (int ks = 0; ks < 8; ++ks) {
    bf16x8 ah[2], al[2], bh[4], bl[4];
#pragma unroll
    for (int rf = 0; rf < 2; ++rf) {
      ah[rf] = *reinterpret_cast<const bf16x8*>(&Ahs[rf * 16 + lr][ks * 32 + lk]);
      al[rf] = *reinterpret_cast<const bf16x8*>(&Als[rf * 16 + lr][ks * 32 + lk]);
    }
#pragma unroll
    for (int cf = 0; cf < 4; ++cf) {
      bh[cf] = pbh[cf][ks * 4];
      bl[cf] = pbl[cf][ks * 4];
    }
#pragma unroll
    for (int rf = 0; rf < 2; ++rf)
#pragma unroll
      for (int cf = 0; cf < 4; ++cf) {
        acc[rf][cf] = __builtin_amdgcn_mfma_f32_16x16x32_bf16(ah[rf], bh[cf], acc[rf][cf], 0, 0, 0);
        acc[rf][cf] = __builtin_amdgcn_mfma_f32_16x16x32_bf16(ah[rf], bl[cf], acc[rf][cf], 0, 0, 0);
        acc[rf][cf] = __builtin_amdgcn_mfma_f32_16x16x32_bf16(al[rf], bh[cf], acc[rf][cf], 0, 0, 0);
      }
  }

  float bias_cf[4];
#pragma unroll
  for (int cf = 0; cf < 4; ++cf) bias_cf[cf] = bias[w * 64 + cf * 16 + lr];

#pragma unroll
  for (int rf = 0; rf < 2; ++rf) {
    const int row0 = bm + rf * 16 + (l >> 4) * 4;
#pragma unroll
    for (int r = 0; r < 4; ++r) {
      const int row = row0 + r;
      if (row < N_Q) {
#pragma unroll
        for (int cf = 0; cf < 4; ++cf) {
          const int col = w * 64 + cf * 16 + lr;
          C[(size_t)row * 256 + col] = acc[rf][cf][r] + bias_cf[cf];
        }
      }
    }
  }
}

// ---------------------------------------------------------------------------
extern "C" void kernel_launch(void* const* d_in, const int* in_sizes, int n_in,
                              void* d_out, int out_size, void* d_ws, size_t ws_size,
                              hipStream_t stream) {
  const float* query = (const float*)d_in[0];
  const float* feats = (const float*)d_in[1];
  const float* refp  = (const float*)d_in[2];
  const int*   mask  = (const int*)d_in[3];
  const float* oW    = (const float*)d_in[4];
  const float* ob    = (const float*)d_in[5];
  const float* wW    = (const float*)d_in[6];
  const float* wb    = (const float*)d_in[7];
  const float* outW  = (const float*)d_in[8];
  const float* outb  = (const float*)d_in[9];
  float* out = (float*)d_out;

  char* wsb = (char*)d_ws;
  size_t o = 0;
  unsigned short* ft = (unsigned short*)(wsb + o); o += (size_t)N_CAM * NPIX * 256 * 2;
  unsigned short* oWth  = (unsigned short*)(wsb + o); o += 256 * 256 * 2;
  unsigned short* oWtl  = (unsigned short*)(wsb + o); o += 256 * 256 * 2;
  unsigned short* wWth  = (unsigned short*)(wsb + o); o += 128 * 256 * 2;
  unsigned short* wWtl  = (unsigned short*)(wsb + o); o += 128 * 256 * 2;
  unsigned short* outWth = (unsigned short*)(wsb + o); o += 256 * 256 * 2;
  unsigned short* outWtl = (unsigned short*)(wsb + o); o += 256 * 256 * 2;
  float* offs    = (float*)(wsb + o); o += (size_t)N_Q * 256 * 4;
  float* wlog    = (float*)(wsb + o); o += (size_t)N_Q * 128 * 4;
  unsigned short* partial = (unsigned short*)(wsb + o);
  o += (size_t)N_CAM * N_Q * 256 * 2;                                      // 30.7 MB

  wprep_k<<<640, 256, 0, stream>>>(oW, wW, outW,
                                   oWth, oWtl, wWth, wWtl, outWth, outWtl);

  fused_prep_gemm_k<<<TRANS_BLKS + G12_BLKS, 256, 0, stream>>>(
      feats, query, ft, oWth, oWtl, ob, offs, wWth, wWtl, wb, wlog);

  sample_cam<<<N_CAM * N_Q, 128, 0, stream>>>(ft, offs, wlog, refp, mask,
                                              partial);

  gemm_out_k<<<(N_Q + OUT_ROWS - 1) / OUT_ROWS, 256, 0, stream>>>(
      partial, mask, outWth, outWtl, outb, out);
}